// Round 7
// baseline (311.178 us; speedup 1.0000x reference)
//
#include <hip/hip_runtime.h>
#include <hip/hip_bf16.h>
#include <cstdint>

#define NB 4
#define TT 2048
#define DM 1024
#define NH 16
#define HD 64
#define QBLK 128
#define KVB 64

typedef __attribute__((ext_vector_type(8))) short bf16x8;
typedef __attribute__((ext_vector_type(4))) float f32x4;
typedef __attribute__((ext_vector_type(16))) float f32x16;
typedef __attribute__((ext_vector_type(4))) float float4v;
typedef __attribute__((ext_vector_type(4))) int i32x4;

static __device__ __forceinline__ unsigned short f2bf(float x) {
    unsigned int u = __float_as_uint(x);
    unsigned int r = (u + 0x7fffu + ((u >> 16) & 1u)) >> 16;
    return (unsigned short)r;
}
static __device__ __forceinline__ uint32_t pk2bf(float lo, float hi) {
    return (uint32_t)f2bf(lo) | ((uint32_t)f2bf(hi) << 16);
}
// packed f32->bf16 pair via HIP cast (RNE, compiler may fuse to v_cvt_pk_bf16_f32)
static __device__ __forceinline__ uint32_t cvtpk(float a, float b) {
    union { __hip_bfloat16 h; unsigned short u; } ca, cb;
    ca.h = __float2bfloat16(a);
    cb.h = __float2bfloat16(b);
    return (uint32_t)ca.u | ((uint32_t)cb.u << 16);
}

#define GLOAD16(gp, lp) __builtin_amdgcn_global_load_lds(                 \
    (const __attribute__((address_space(1))) void*)(gp),                  \
    (__attribute__((address_space(3))) void*)(lp), 16, 0, 0)
#define BAR() asm volatile("s_barrier" ::: "memory")
#define WAITV6() asm volatile("s_waitcnt vmcnt(6)" ::: "memory")
#define WAITV4() asm volatile("s_waitcnt vmcnt(4)" ::: "memory")
#define WAITV0() asm volatile("s_waitcnt vmcnt(0)" ::: "memory")

// ---- W[k][n] f32 -> Wt[n][k] bf16 (transpose + convert) ----
__global__ __launch_bounds__(256) void k_transpose_w(const float* __restrict__ W,
                                                     unsigned short* __restrict__ Wt) {
    __shared__ unsigned short tile[32][33];
    int tx = threadIdx.x, ty = threadIdx.y;
    int kb = blockIdx.x * 32, nb = blockIdx.y * 32;
#pragma unroll
    for (int i = 0; i < 4; ++i)
        tile[ty + i * 8][tx] = f2bf(W[(size_t)(kb + ty + i * 8) * DM + nb + tx]);
    __syncthreads();
#pragma unroll
    for (int i = 0; i < 4; ++i)
        Wt[(size_t)(nb + ty + i * 8) * DM + kb + tx] = tile[tx][ty + i * 8];
}

// ---- V[bh][t][d] bf16 -> Vt[bh][d][t] bf16 ----
__global__ __launch_bounds__(256) void k_transpose_v(const unsigned short* __restrict__ V,
                                                     unsigned short* __restrict__ Vt) {
    __shared__ unsigned short tile[32][34];
    int tx = threadIdx.x, ty = threadIdx.y;
    int bh = blockIdx.z;
    int t0 = blockIdx.x * 32, d0 = blockIdx.y * 32;
    const unsigned short* src = V + (size_t)bh * TT * HD;
    unsigned short* dst = Vt + (size_t)bh * HD * TT;
#pragma unroll
    for (int i = 0; i < 4; ++i)
        tile[ty + i * 8][tx] = src[(size_t)(t0 + ty + i * 8) * HD + d0 + tx];
    __syncthreads();
#pragma unroll
    for (int i = 0; i < 4; ++i)
        dst[(size_t)(d0 + ty + i * 8) * TT + t0 + tx] = tile[tx][ty + i * 8];
}

// ---- GEMM: C[8192][1024] = A[8192][1024] @ W[1024][1024] (+bias)*scale ----
// m97-style: global_load_lds(16B) staging into linear XOR-swizzled LDS,
// raw-barrier double buffer with counted vmcnt (never 0 mid-loop).
// A_F32: A staged as raw f32 (128B rows, XOR (row&7)<<4), converted to bf16
// at fragment read. Else A is bf16 (64B rows, XOR (row&3)<<4). B always bf16.
// OUT_MODE 0: scatter bf16 to [b,h,t,d]; 1: f32 row-major.
template <int OUT_MODE, bool A_F32>
__global__ __launch_bounds__(256) void k_gemm(const void* __restrict__ Av,
                                              const unsigned short* __restrict__ Bt,
                                              const float* __restrict__ bias,
                                              void* __restrict__ Cv, float scale) {
    constexpr int ABUF = A_F32 ? 16384 : 8192;
    __shared__ __align__(16) char Asl[2][ABUF];
    __shared__ __align__(16) char Bsl[2][8192];
    const int tid = threadIdx.x;
    const int lane = tid & 63, wid = tid >> 6;
    const int lg = lane >> 4, lc = lane & 15;
    const int wm = wid >> 1, wn = wid & 1;
    const int m0 = blockIdx.x * 128, n0 = blockIdx.y * 128;

    const char* Ab = (const char*)Av;
    const char* Bb = (const char*)Bt;

    f32x4 acc[4][4];
#pragma unroll
    for (int mi = 0; mi < 4; ++mi)
#pragma unroll
        for (int ni = 0; ni < 4; ++ni)
            acc[mi][ni] = (f32x4){0.f, 0.f, 0.f, 0.f};

    auto stage = [&](int buf, int k0) {
        if (A_F32) {
#pragma unroll
            for (int j = 0; j < 4; ++j) {  // 128 rows x 128B (32 f32)
                const int row = j * 32 + (tid >> 3);
                const int swz = ((tid & 7) * 16) ^ ((row & 7) << 4);
                GLOAD16(Ab + (size_t)(m0 + row) * (DM * 4) + k0 * 4 + swz,
                        &Asl[buf][0] + j * 4096 + tid * 16);
            }
        } else {
#pragma unroll
            for (int j = 0; j < 2; ++j) {  // 128 rows x 64B (32 bf16)
                const int row = j * 64 + (tid >> 2);
                const int swz = ((tid & 3) * 16) ^ ((row & 3) << 4);
                GLOAD16(Ab + (size_t)(m0 + row) * (DM * 2) + k0 * 2 + swz,
                        &Asl[buf][0] + j * 4096 + tid * 16);
            }
        }
#pragma unroll
        for (int j = 0; j < 2; ++j) {
            const int row = j * 64 + (tid >> 2);
            const int swz = ((tid & 3) * 16) ^ ((row & 3) << 4);
            GLOAD16(Bb + (size_t)(n0 + row) * (DM * 2) + k0 * 2 + swz,
                    &Bsl[buf][0] + j * 4096 + tid * 16);
        }
    };

    stage(0, 0);
    __syncthreads();  // drains vmcnt(0) for the prologue tile

    int cur = 0;
    for (int t = 0; t < DM / 32; ++t) {
        if (t + 1 < DM / 32) {
            stage(cur ^ 1, (t + 1) * 32);
            if (A_F32) { WAITV6(); } else { WAITV4(); }  // current tile done
        } else {
            WAITV0();
        }
        BAR();

        bf16x8 af[4], bfr[4];
#pragma unroll
        for (int ni = 0; ni < 4; ++ni) {
            const int n = wn * 64 + ni * 16 + lc;
            bfr[ni] = *(const bf16x8*)(&Bsl[cur][0] + n * 64 + ((lg * 16) ^ ((n & 3) << 4)));
        }
#pragma unroll
        for (int mi = 0; mi < 4; ++mi) {
            const int m = wm * 64 + mi * 16 + lc;
            if (A_F32) {
                const char* rp = &Asl[cur][0] + m * 128;
                const int x = (m & 7) << 4;
                float4v v0 = *(const float4v*)(rp + ((lg * 32) ^ x));
                float4v v1 = *(const float4v*)(rp + ((lg * 32 + 16) ^ x));
                i32x4 pf = {(int)cvtpk(v0[0], v0[1]), (int)cvtpk(v0[2], v0[3]),
                            (int)cvtpk(v1[0], v1[1]), (int)cvtpk(v1[2], v1[3])};
                af[mi] = *(bf16x8*)&pf;
            } else {
                af[mi] = *(const bf16x8*)(&Asl[cur][0] + m * 64 + ((lg * 16) ^ ((m & 3) << 4)));
            }
        }
        __builtin_amdgcn_s_setprio(1);
#pragma unroll
        for (int mi = 0; mi < 4; ++mi)
#pragma unroll
            for (int ni = 0; ni < 4; ++ni)
                acc[mi][ni] = __builtin_amdgcn_mfma_f32_16x16x32_bf16(af[mi], bfr[ni],
                                                                      acc[mi][ni], 0, 0, 0);
        __builtin_amdgcn_s_setprio(0);
        BAR();
        cur ^= 1;
    }

#pragma unroll
    for (int mi = 0; mi < 4; ++mi)
#pragma unroll
        for (int ni = 0; ni < 4; ++ni)
#pragma unroll
            for (int r = 0; r < 4; ++r) {
                int m = m0 + wm * 64 + mi * 16 + lg * 4 + r;
                int n = n0 + wn * 64 + ni * 16 + lc;
                float val = (acc[mi][ni][r] + bias[n]) * scale;
                if (OUT_MODE == 0) {
                    int b = m >> 11, t = m & (TT - 1), h = n >> 6, d = n & 63;
                    ((unsigned short*)Cv)[(((size_t)b * NH + h) * TT + t) * HD + d] = f2bf(val);
                } else {
                    ((float*)Cv)[(size_t)m * DM + n] = val;
                }
            }
}

// ---- flash attention, swapped-QK^T 32x32 MFMA, in-register softmax ----
// 4 waves x 32 q-rows (QBLK=128), 1024 blocks -> 4 blocks/CU.
// K [key][d], V^T [d][key] in XOR-swizzled double-buffered LDS (byte^=(row&7)<<4),
// staged via global_load_lds with pre-swizzled source, counted vmcnt(4).
// S^T = mfma(K, Q): col=lane&31=q, reg r holds key (r&3)+8*(r>>2)+4*(lane>>5).
__global__ __launch_bounds__(256) void k_attn(const unsigned short* __restrict__ Qg,
                                              const unsigned short* __restrict__ Kg,
                                              const unsigned short* __restrict__ Vtg,
                                              const int* __restrict__ pm,
                                              unsigned short* __restrict__ Og) {
    __shared__ __align__(16) unsigned short Kl[2][KVB * HD];  // 8 KB per buf
    __shared__ __align__(16) unsigned short Vl[2][KVB * HD];  // V^T tile [d][key]
    __shared__ uint64_t pmbits[TT / 64];

    const int bh = blockIdx.y;
    const int b = bh >> 4, h = bh & 15;
    const int qb = gridDim.x - 1 - blockIdx.x;  // heavy blocks first
    const int qbase = qb * QBLK;
    const int tid = threadIdx.x;
    const int wid = tid >> 6, lane = tid & 63;
    const int hi = lane >> 5, l31 = lane & 31;
    const int q0 = qbase + wid * 32;
    const int q = q0 + l31;

    const unsigned short* Qh = Qg + (size_t)bh * TT * HD;
    const char* Khb = (const char*)(Kg + (size_t)bh * TT * HD);
    const char* Vthb = (const char*)(Vtg + (size_t)bh * HD * TT);
    const int* pmb = pm + b * TT;

    char* const kdst = (char*)&Kl[0][0];
    char* const vdst = (char*)&Vl[0][0];

#define ASTAGE(buf, kv0)                                                        \
    {                                                                           \
        _Pragma("unroll")                                                       \
        for (int j = 0; j < 2; ++j) {                                           \
            const int rr = j * 32 + (tid >> 3);                                 \
            const int swz = ((tid & 7) * 16) ^ ((rr & 7) << 4);                 \
            GLOAD16(Khb + (size_t)((kv0) + rr) * 128 + swz,                     \
                    kdst + (buf) * 8192 + j * 4096 + tid * 16);                 \
            GLOAD16(Vthb + (size_t)rr * (TT * 2) + (size_t)(kv0) * 2 + swz,     \
                    vdst + (buf) * 8192 + j * 4096 + tid * 16);                 \
        }                                                                       \
    }

    // prologue: stage tile 0 (drained by the __syncthreads below)
    ASTAGE(0, 0);

    // padding-mask bitmasks (one u64 per 64-key tile); bit=1 -> key valid
#pragma unroll
    for (int it = 0; it < 8; ++it) {
        const int g = it * 4 + wid;
        unsigned long long msk = __ballot(pmb[g * 64 + lane] != 0);
        if (lane == 0) pmbits[g] = msk;
    }

    // hoist Q fragments (B-operand: col q = lane&31, d-chunk dd*16 + hi*8)
    bf16x8 qf[4];
#pragma unroll
    for (int dd = 0; dd < 4; ++dd)
        qf[dd] = *(const bf16x8*)((const char*)Qh + (size_t)q * 128 + dd * 32 + hi * 16);

    f32x16 o0, o1;
#pragma unroll
    for (int r = 0; r < 16; ++r) { o0[r] = 0.f; o1[r] = 0.f; }
    float mrow = -INFINITY, lrow = 0.f;

    __syncthreads();  // pmbits visible; tile-0 loads drained (vmcnt 0)

    const int nt = (qbase + QBLK) >> 6;
    int cur = 0;
    for (int t = 0; t < nt; ++t) {
        const int kv0 = t << 6;
        if (t + 1 < nt) {
            ASTAGE(cur ^ 1, kv0 + KVB);
            WAITV4();  // current tile's 4 loads done; next tile's 4 in flight
        } else {
            WAITV0();
        }
        BAR();

        if (kv0 <= q0 + 31) {  // wave-uniform causal skip
            const uint64_t vb = pmbits[kv0 >> 6];
            const uint32_t pm0 = ((uint32_t)vb) >> (4 * hi);
            const uint32_t pm1 = ((uint32_t)(vb >> 32)) >> (4 * hi);
            const bool allvalid = (vb == ~0ull);
            const bool do2 = (kv0 + 32 <= q0 + 31);
            const bool needmask = (kv0 + 63 > q0) || !allvalid;
            const char* kb = (const char*)&Kl[0][0] + cur * 8192;
            const char* vbp = (const char*)&Vl[0][0] + cur * 8192;

            // ---- QK^T: S^T[key][q] ----
            f32x16 st0, st1;
#pragma unroll
            for (int r = 0; r < 16; ++r) { st0[r] = 0.f; st1[r] = 0.f; }
            __builtin_amdgcn_s_setprio(1);
#pragma unroll
            for (int dd = 0; dd < 4; ++dd) {
                const int row = l31;
                bf16x8 kf = *(const bf16x8*)(kb + row * 128 + ((dd * 32 + hi * 16) ^ ((row & 7) << 4)));
                st0 = __builtin_amdgcn_mfma_f32_32x32x16_bf16(kf, qf[dd], st0, 0, 0, 0);
            }
            if (do2) {
#pragma unroll
                for (int dd = 0; dd < 4; ++dd) {
                    const int row = 32 + l31;
                    bf16x8 kf = *(const bf16x8*)(kb + row * 128 + ((dd * 32 + hi * 16) ^ ((row & 7) << 4)));
                    st1 = __builtin_amdgcn_mfma_f32_32x32x16_bf16(kf, qf[dd], st1, 0, 0, 0);
                }
            }
            __builtin_amdgcn_s_setprio(0);

            // ---- masking (causal + padding), lane-local ----
            const int qr = q - kv0 - 4 * hi;
            if (needmask) {
#pragma unroll
                for (int r = 0; r < 16; ++r) {
                    const int c = (r & 3) + 8 * (r >> 2);
                    st0[r] = (((pm0 >> c) & 1) && (c <= qr)) ? st0[r] : -INFINITY;
                }
                if (do2) {
#pragma unroll
                    for (int r = 0; r < 16; ++r) {
                        const int c = (r & 3) + 8 * (r >> 2);
                        st1[r] = (((pm1 >> c) & 1) && (c + 32 <= qr)) ? st1[r] : -INFINITY;
                    }
                }
            }

            // ---- online softmax, fully in-register ----
            float mloc = -INFINITY;
#pragma unroll
            for (int r = 0; r < 16; ++r) mloc = fmaxf(mloc, st0[r]);
            if (do2) {
#pragma unroll
                for (int r = 0; r < 16; ++r) mloc = fmaxf(mloc, st1[r]);
            }
            const float cmax = fmaxf(mloc, __shfl_xor(mloc, 32, 64));
            const float mnew = fmaxf(mrow, cmax);
            const float msafe = fmaxf(mnew, -1.0e30f);  // finite stand-in
            const float esc = __builtin_amdgcn_exp2f(mrow - msafe);  // -inf -> 0
#pragma unroll
            for (int r = 0; r < 16; ++r) { o0[r] *= esc; o1[r] *= esc; }
            lrow *= esc;
            mrow = mnew;

            // exponentials (masked -inf entries -> exp2(-inf) = 0; msafe finite)
            float tot = 0.f;
#pragma unroll
            for (int r = 0; r < 16; ++r) {
                st0[r] = __builtin_amdgcn_exp2f(st0[r] - msafe);
                tot += st0[r];
            }
            if (do2) {
#pragma unroll
                for (int r = 0; r < 16; ++r) {
                    st1[r] = __builtin_amdgcn_exp2f(st1[r] - msafe);
                    tot += st1[r];
                }
            }
            lrow += tot + __shfl_xor(tot, 32, 64);

            // ---- P -> bf16 B-fragments (pair redistribution via shfl) + PV ----
            __builtin_amdgcn_s_setprio(1);
#pragma unroll
            for (int kc = 0; kc < 2; ++kc) {
                uint32_t A0 = pk2bf(st0[kc * 8 + 0], st0[kc * 8 + 1]);
                uint32_t A1 = pk2bf(st0[kc * 8 + 2], st0[kc * 8 + 3]);
                uint32_t C0 = pk2bf(st0[kc * 8 + 4], st0[kc * 8 + 5]);
                uint32_t C1 = pk2bf(st0[kc * 8 + 6], st0[kc * 8 + 7]);
                uint32_t oA0 = __shfl_xor(A0, 32, 64), oA1 = __shfl_xor(A1, 32, 64);
                uint32_t oC0 = __shfl_xor(C0, 32, 64), oC1 = __shfl_xor(C1, 32, 64);
                i32x4 pf = {(int)(hi ? oC0 : A0), (int)(hi ? oC1 : A1),
                            (int)(hi ? C0 : oA0), (int)(hi ? C1 : oA1)};
                bf16x8 pb = *(bf16x8*)&pf;
                const int colb = kc * 32 + hi * 16;
                {
                    const int row = l31;
                    bf16x8 vf = *(const bf16x8*)(vbp + row * 128 + (colb ^ ((row & 7) << 4)));
                    o0 = __builtin_amdgcn_mfma_f32_32x32x16_bf16(vf, pb, o0, 0, 0, 0);
                }
                {
                    const int row = 32 + l31;
                    bf16x8 vf = *(const bf16x8*)(vbp + row * 128 + (colb ^ ((row & 7) << 4)));
                    o1 = __builtin_amdgcn_mfma_f32_32x32x16_bf16(vf, pb, o1, 0, 0, 0);
                }
            }
            if (do2) {
#pragma unroll
                for (int kc = 0; kc < 2; ++kc) {
                    uint32_t A0 = pk2bf(st1[kc * 8 + 0], st1[kc * 8 + 1]);
                    uint32_t A1 = pk2bf(st1[kc * 8 + 2], st1[kc * 8 + 3]);
                    uint32_t C0 = pk2bf(st1[kc * 8 + 4], st1[kc * 8 + 5]);
                    uint32_t C1 = pk2bf(st1[kc * 8 + 6], st1[kc * 8 + 7]);
                    uint32_t oA0 = __shfl_xor(A0, 32, 64), oA1 = __shfl_xor(A1, 32, 64);
                    uint32_t oC0 = __shfl_xor(C0, 32, 64), oC1 = __shfl_xor(C1, 32, 64);
                    i32x4 pf = {(int)(hi ? oC0 : A0), (int)(hi ? oC1 : A1),
                                (int)(hi ? C0 : oA0), (int)(hi ? C1 : oA1)};
                    bf16x8 pb = *(bf16x8*)&pf;
                    const int colb = (2 + kc) * 32 + hi * 16;
                    {
                        const int row = l31;
                        bf16x8 vf = *(const bf16x8*)(vbp + row * 128 + (colb ^ ((row & 7) << 4)));
                        o0 = __builtin_amdgcn_mfma_f32_32x32x16_bf16(vf, pb, o0, 0, 0, 0);
                    }
                    {
                        const int row = 32 + l31;
                        bf16x8 vf = *(const bf16x8*)(vbp + row * 128 + (colb ^ ((row & 7) << 4)));
                        o1 = __builtin_amdgcn_mfma_f32_32x32x16_bf16(vf, pb, o1, 0, 0, 0);
                    }
                }
            }
            __builtin_amdgcn_s_setprio(0);
        }
        BAR();
        cur ^= 1;
    }

    // ---- epilogue: normalize, write bf16 [b*T+q][h*64+d], 8B packed stores ----
    const float inv = (lrow > 0.f) ? (1.0f / lrow) : 0.f;
    unsigned short* orow = Og + ((size_t)(b * TT + q)) * DM + h * HD;
#pragma unroll
    for (int g4 = 0; g4 < 4; ++g4) {
        uint32_t w0 = pk2bf(o0[g4 * 4 + 0] * inv, o0[g4 * 4 + 1] * inv);
        uint32_t w1 = pk2bf(o0[g4 * 4 + 2] * inv, o0[g4 * 4 + 3] * inv);
        *(uint2*)(orow + g4 * 8 + 4 * hi) = make_uint2(w0, w1);
    }
#pragma unroll
    for (int g4 = 0; g4 < 4; ++g4) {
        uint32_t w0 = pk2bf(o1[g4 * 4 + 0] * inv, o1[g4 * 4 + 1] * inv);
        uint32_t w1 = pk2bf(o1[g4 * 4 + 2] * inv, o1[g4 * 4 + 3] * inv);
        *(uint2*)(orow + 32 + g4 * 8 + 4 * hi) = make_uint2(w0, w1);
    }
}

extern "C" void kernel_launch(void* const* d_in, const int* in_sizes, int n_in,
                              void* d_out, int out_size, void* d_ws, size_t ws_size,
                              hipStream_t stream) {
    const float* xq = (const float*)d_in[0];
    const float* xk = (const float*)d_in[1];
    const float* xv = (const float*)d_in[2];
    const int* pmask = (const int*)d_in[3];
    const float* Wq = (const float*)d_in[4];
    const float* bq = (const float*)d_in[5];
    const float* Wk = (const float*)d_in[6];
    const float* bk = (const float*)d_in[7];
    const float* Wv = (const float*)d_in[8];
    const float* bv = (const float*)d_in[9];
    const float* Wo = (const float*)d_in[10];
    const float* bo = (const float*)d_in[11];

    char* ws = (char*)d_ws;
    const size_t WT = (size_t)DM * DM * 2;             // 2 MB per transposed weight
    const size_t QKV = (size_t)NB * NH * TT * HD * 2;  // 16 MB each
    unsigned short* WqT = (unsigned short*)(ws + 0 * WT);
    unsigned short* WkT = (unsigned short*)(ws + 1 * WT);
    unsigned short* WvT = (unsigned short*)(ws + 2 * WT);
    unsigned short* WoT = (unsigned short*)(ws + 3 * WT);
    unsigned short* Qb = (unsigned short*)(ws + 4 * WT);
    unsigned short* Kb = (unsigned short*)(ws + 4 * WT + QKV);
    unsigned short* Vb = (unsigned short*)(ws + 4 * WT + 2 * QKV);
    unsigned short* Vt = (unsigned short*)(ws + 4 * WT + 3 * QKV);
    unsigned short* Ob = Vb;  // Vb dead after k_transpose_v; reuse for attn out

    dim3 tb(32, 8);
    k_transpose_w<<<dim3(32, 32), tb, 0, stream>>>(Wq, WqT);
    k_transpose_w<<<dim3(32, 32), tb, 0, stream>>>(Wk, WkT);
    k_transpose_w<<<dim3(32, 32), tb, 0, stream>>>(Wv, WvT);
    k_transpose_w<<<dim3(32, 32), tb, 0, stream>>>(Wo, WoT);

    const float qscale = 0.125f * 1.44269504088896340736f;  // 1/sqrt(64) * log2(e)
    dim3 gg(64, 8);  // M/128, N/128
    k_gemm<0, true><<<gg, 256, 0, stream>>>(xq, WqT, bq, Qb, qscale);
    k_gemm<0, true><<<gg, 256, 0, stream>>>(xk, WkT, bk, Kb, 1.0f);
    k_gemm<0, true><<<gg, 256, 0, stream>>>(xv, WvT, bv, Vb, 1.0f);

    k_transpose_v<<<dim3(TT / 32, HD / 32, NB * NH), tb, 0, stream>>>(Vb, Vt);

    k_attn<<<dim3(TT / QBLK, NB * NH), 256, 0, stream>>>(Qb, Kb, Vt, pmask, Ob);

    k_gemm<1, false><<<gg, 256, 0, stream>>>(Ob, WoT, bo, d_out, 1.0f);
}

// Round 8
// 275.142 us; speedup vs baseline: 1.1310x; 1.1310x over previous
//
#include <hip/hip_runtime.h>
#include <hip/hip_bf16.h>
#include <cstdint>

#define NB 4
#define TT 2048
#define DM 1024
#define NH 16
#define HD 64
#define QBLK 256
#define KVB 64

typedef __attribute__((ext_vector_type(8))) short bf16x8;
typedef __attribute__((ext_vector_type(4))) float f32x4;
typedef __attribute__((ext_vector_type(16))) float f32x16;
typedef __attribute__((ext_vector_type(4))) float float4v;
typedef __attribute__((ext_vector_type(4))) int i32x4;

static __device__ __forceinline__ unsigned short f2bf(float x) {
    unsigned int u = __float_as_uint(x);
    unsigned int r = (u + 0x7fffu + ((u >> 16) & 1u)) >> 16;
    return (unsigned short)r;
}
static __device__ __forceinline__ uint32_t pk2bf(float lo, float hi) {
    return (uint32_t)f2bf(lo) | ((uint32_t)f2bf(hi) << 16);
}

#define GLOAD16(gp, lp) __builtin_amdgcn_global_load_lds(                 \
    (const __attribute__((address_space(1))) void*)(gp),                  \
    (__attribute__((address_space(3))) void*)(lp), 16, 0, 0)
#define BAR() asm volatile("s_barrier" ::: "memory")
#define WAITV4() asm volatile("s_waitcnt vmcnt(4)" ::: "memory")
#define WAITV2() asm volatile("s_waitcnt vmcnt(2)" ::: "memory")
#define WAITV0() asm volatile("s_waitcnt vmcnt(0)" ::: "memory")

// ---- f32 -> bf16 bulk convert (8 elems/thread/iter) ----
__global__ __launch_bounds__(256) void k_cvt_bf16(const float* __restrict__ src,
                                                  unsigned short* __restrict__ dst,
                                                  int n8) {
    int i = blockIdx.x * 256 + threadIdx.x;
    const int stride = gridDim.x * 256;
    for (; i < n8; i += stride) {
        const float4v* s = (const float4v*)(src + (size_t)i * 8);
        float4v v0 = s[0], v1 = s[1];
        uint4 o;
        o.x = pk2bf(v0[0], v0[1]);
        o.y = pk2bf(v0[2], v0[3]);
        o.z = pk2bf(v1[0], v1[1]);
        o.w = pk2bf(v1[2], v1[3]);
        *(uint4*)(dst + (size_t)i * 8) = o;
    }
}

// ---- W[k][n] f32 -> Wt[n][k] bf16 (transpose + convert) ----
__global__ __launch_bounds__(256) void k_transpose_w(const float* __restrict__ W,
                                                     unsigned short* __restrict__ Wt) {
    __shared__ unsigned short tile[32][33];
    int tx = threadIdx.x, ty = threadIdx.y;
    int kb = blockIdx.x * 32, nb = blockIdx.y * 32;
#pragma unroll
    for (int i = 0; i < 4; ++i)
        tile[ty + i * 8][tx] = f2bf(W[(size_t)(kb + ty + i * 8) * DM + nb + tx]);
    __syncthreads();
#pragma unroll
    for (int i = 0; i < 4; ++i)
        Wt[(size_t)(nb + ty + i * 8) * DM + kb + tx] = tile[tx][ty + i * 8];
}

// ---- V[bh][t][d] bf16 -> Vt[bh][d][t] bf16 ----
__global__ __launch_bounds__(256) void k_transpose_v(const unsigned short* __restrict__ V,
                                                     unsigned short* __restrict__ Vt) {
    __shared__ unsigned short tile[32][34];
    int tx = threadIdx.x, ty = threadIdx.y;
    int bh = blockIdx.z;
    int t0 = blockIdx.x * 32, d0 = blockIdx.y * 32;
    const unsigned short* src = V + (size_t)bh * TT * HD;
    unsigned short* dst = Vt + (size_t)bh * HD * TT;
#pragma unroll
    for (int i = 0; i < 4; ++i)
        tile[ty + i * 8][tx] = src[(size_t)(t0 + ty + i * 8) * HD + d0 + tx];
    __syncthreads();
#pragma unroll
    for (int i = 0; i < 4; ++i)
        dst[(size_t)(d0 + ty + i * 8) * TT + t0 + tx] = tile[tx][ty + i * 8];
}

// ---- GEMM: C[8192][1024] = A_bf16[8192][1024] @ W[1024][1024] (+bias)*scale ----
// m97-style: global_load_lds(16B) into XOR-swizzled LDS (64B rows,
// byte ^= (row&3)<<4), raw-barrier double buffer, counted vmcnt(4).
// OUT_MODE 0: scatter bf16 to [b,h,t,d]; 1: f32 row-major.
template <int OUT_MODE>
__global__ __launch_bounds__(256) void k_gemm(const unsigned short* __restrict__ A,
                                              const unsigned short* __restrict__ Bt,
                                              const float* __restrict__ bias,
                                              void* __restrict__ Cv, float scale) {
    __shared__ __align__(16) char Asl[2][8192];
    __shared__ __align__(16) char Bsl[2][8192];
    const int tid = threadIdx.x;
    const int lane = tid & 63, wid = tid >> 6;
    const int lg = lane >> 4, lc = lane & 15;
    const int wm = wid >> 1, wn = wid & 1;
    const int m0 = blockIdx.x * 128, n0 = blockIdx.y * 128;

    const char* Ab = (const char*)A;
    const char* Bb = (const char*)Bt;

    f32x4 acc[4][4];
#pragma unroll
    for (int mi = 0; mi < 4; ++mi)
#pragma unroll
        for (int ni = 0; ni < 4; ++ni)
            acc[mi][ni] = (f32x4){0.f, 0.f, 0.f, 0.f};

    auto stage = [&](int buf, int k0) {
#pragma unroll
        for (int j = 0; j < 2; ++j) {
            const int row = j * 64 + (tid >> 2);
            const int swz = ((tid & 3) * 16) ^ ((row & 3) << 4);
            GLOAD16(Ab + (size_t)(m0 + row) * (DM * 2) + k0 * 2 + swz,
                    &Asl[buf][0] + j * 4096 + tid * 16);
            GLOAD16(Bb + (size_t)(n0 + row) * (DM * 2) + k0 * 2 + swz,
                    &Bsl[buf][0] + j * 4096 + tid * 16);
        }
    };

    stage(0, 0);
    __syncthreads();  // drains vmcnt(0) for the prologue tile

    int cur = 0;
    for (int t = 0; t < DM / 32; ++t) {
        if (t + 1 < DM / 32) {
            stage(cur ^ 1, (t + 1) * 32);
            WAITV4();  // current tile's 4 loads done; next tile's 4 in flight
        } else {
            WAITV0();
        }
        BAR();

        bf16x8 af[4], bfr[4];
#pragma unroll
        for (int ni = 0; ni < 4; ++ni) {
            const int n = wn * 64 + ni * 16 + lc;
            bfr[ni] = *(const bf16x8*)(&Bsl[cur][0] + n * 64 + ((lg * 16) ^ ((n & 3) << 4)));
        }
#pragma unroll
        for (int mi = 0; mi < 4; ++mi) {
            const int m = wm * 64 + mi * 16 + lc;
            af[mi] = *(const bf16x8*)(&Asl[cur][0] + m * 64 + ((lg * 16) ^ ((m & 3) << 4)));
        }
        __builtin_amdgcn_s_setprio(1);
#pragma unroll
        for (int mi = 0; mi < 4; ++mi)
#pragma unroll
            for (int ni = 0; ni < 4; ++ni)
                acc[mi][ni] = __builtin_amdgcn_mfma_f32_16x16x32_bf16(af[mi], bfr[ni],
                                                                      acc[mi][ni], 0, 0, 0);
        __builtin_amdgcn_s_setprio(0);
        BAR();
        cur ^= 1;
    }

#pragma unroll
    for (int mi = 0; mi < 4; ++mi)
#pragma unroll
        for (int ni = 0; ni < 4; ++ni)
#pragma unroll
            for (int r = 0; r < 4; ++r) {
                int m = m0 + wm * 64 + mi * 16 + lg * 4 + r;
                int n = n0 + wn * 64 + ni * 16 + lc;
                float val = (acc[mi][ni][r] + bias[n]) * scale;
                if (OUT_MODE == 0) {
                    int b = m >> 11, t = m & (TT - 1), h = n >> 6, d = n & 63;
                    ((unsigned short*)Cv)[(((size_t)b * NH + h) * TT + t) * HD + d] = f2bf(val);
                } else {
                    ((float*)Cv)[(size_t)m * DM + n] = val;
                }
            }
}

// ---- flash attention, swapped-QK^T 32x32 MFMA, in-register softmax ----
// Round-6 config: 8 waves x 32 q-rows (QBLK=256). KV tiles of 64, double-
// buffered XOR-swizzled LDS (byte^=(row&7)<<4), global_load_lds staging with
// pre-swizzled source, counted vmcnt(2).
// S^T = mfma(K, Q): col=lane&31=q, reg r holds key (r&3)+8*(r>>2)+4*(lane>>5).
__global__ __launch_bounds__(512) void k_attn(const unsigned short* __restrict__ Qg,
                                              const unsigned short* __restrict__ Kg,
                                              const unsigned short* __restrict__ Vtg,
                                              const int* __restrict__ pm,
                                              unsigned short* __restrict__ Og) {
    __shared__ __align__(16) unsigned short Kl[2][KVB * HD];  // 8 KB per buf
    __shared__ __align__(16) unsigned short Vl[2][KVB * HD];  // V^T tile [d][key]
    __shared__ uint64_t pmbits[TT / 64];

    const int bh = blockIdx.y;
    const int b = bh >> 4, h = bh & 15;
    const int qb = gridDim.x - 1 - blockIdx.x;  // heavy blocks first
    const int qbase = qb * QBLK;
    const int tid = threadIdx.x;
    const int wid = tid >> 6, lane = tid & 63;
    const int hi = lane >> 5, l31 = lane & 31;
    const int q0 = qbase + wid * 32;
    const int q = q0 + l31;

    const unsigned short* Qh = Qg + (size_t)bh * TT * HD;
    const char* Khb = (const char*)(Kg + (size_t)bh * TT * HD);
    const char* Vthb = (const char*)(Vtg + (size_t)bh * HD * TT);
    const int* pmb = pm + b * TT;

    // staging constants: 1 GLOAD16/thread for K, 1 for V per tile
    const int srow = lane >> 3;                         // 0..7
    const int scolx = ((lane & 7) * 16) ^ (srow << 4);  // pre-swizzled col byte
    char* const kdst = (char*)&Kl[0][0];                // + buf*8192 + wid*1024
    char* const vdst = (char*)&Vl[0][0];

    // prologue: stage tile 0 (drained by the __syncthreads below)
    GLOAD16(Khb + (size_t)(wid * 8 + srow) * 128 + scolx, kdst + wid * 1024);
    GLOAD16(Vthb + (size_t)(wid * 8 + srow) * 4096 + scolx, vdst + wid * 1024);

    // padding-mask bitmasks (one u64 per 64-key tile); bit=1 -> key valid
#pragma unroll
    for (int it = 0; it < 4; ++it) {
        const int g = wid + it * 8;
        unsigned long long msk = __ballot(pmb[g * 64 + lane] != 0);
        if (lane == 0) pmbits[g] = msk;
    }

    // hoist Q fragments (B-operand: col q = lane&31, d-chunk dd*16 + hi*8)
    bf16x8 qf[4];
#pragma unroll
    for (int dd = 0; dd < 4; ++dd)
        qf[dd] = *(const bf16x8*)((const char*)Qh + (size_t)q * 128 + dd * 32 + hi * 16);

    f32x16 o0, o1;
#pragma unroll
    for (int r = 0; r < 16; ++r) { o0[r] = 0.f; o1[r] = 0.f; }
    float mrow = -INFINITY, lrow = 0.f;

    __syncthreads();  // pmbits visible; tile-0 loads drained (vmcnt 0)

    const int nt = (qbase + QBLK) >> 6;
    int cur = 0;
    for (int t = 0; t < nt; ++t) {
        const int kv0 = t << 6;
        if (t + 1 < nt) {
            const int kn = kv0 + KVB;
            const int nb = (cur ^ 1) * 8192 + wid * 1024;
            GLOAD16(Khb + (size_t)(kn + wid * 8 + srow) * 128 + scolx, kdst + nb);
            GLOAD16(Vthb + (size_t)(wid * 8 + srow) * 4096 + (size_t)kn * 2 + scolx, vdst + nb);
            WAITV2();  // current tile's 2 loads done; next tile's 2 in flight
        } else {
            WAITV0();
        }
        BAR();

        if (kv0 <= q0 + 31) {  // wave-uniform causal skip
            const uint64_t vb = pmbits[kv0 >> 6];
            const uint32_t pm0 = ((uint32_t)vb) >> (4 * hi);
            const uint32_t pm1 = ((uint32_t)(vb >> 32)) >> (4 * hi);
            const bool allvalid = (vb == ~0ull);
            const bool do2 = (kv0 + 32 <= q0 + 31);
            const bool needmask = (kv0 + 63 > q0) || !allvalid;
            const char* kb = (const char*)&Kl[0][0] + cur * 8192;
            const char* vbp = (const char*)&Vl[0][0] + cur * 8192;

            // ---- QK^T: S^T[key][q] ----
            f32x16 st0, st1;
#pragma unroll
            for (int r = 0; r < 16; ++r) { st0[r] = 0.f; st1[r] = 0.f; }
            __builtin_amdgcn_s_setprio(1);
#pragma unroll
            for (int dd = 0; dd < 4; ++dd) {
                const int row = l31;
                bf16x8 kf = *(const bf16x8*)(kb + row * 128 + ((dd * 32 + hi * 16) ^ ((row & 7) << 4)));
                st0 = __builtin_amdgcn_mfma_f32_32x32x16_bf16(kf, qf[dd], st0, 0, 0, 0);
            }
            if (do2) {
#pragma unroll
                for (int dd = 0; dd < 4; ++dd) {
                    const int row = 32 + l31;
                    bf16x8 kf = *(const bf16x8*)(kb + row * 128 + ((dd * 32 + hi * 16) ^ ((row & 7) << 4)));
                    st1 = __builtin_amdgcn_mfma_f32_32x32x16_bf16(kf, qf[dd], st1, 0, 0, 0);
                }
            }
            __builtin_amdgcn_s_setprio(0);

            // ---- masking (causal + padding), lane-local ----
            const int qr = q - kv0 - 4 * hi;
            if (needmask) {
#pragma unroll
                for (int r = 0; r < 16; ++r) {
                    const int c = (r & 3) + 8 * (r >> 2);
                    st0[r] = (((pm0 >> c) & 1) && (c <= qr)) ? st0[r] : -INFINITY;
                }
                if (do2) {
#pragma unroll
                    for (int r = 0; r < 16; ++r) {
                        const int c = (r & 3) + 8 * (r >> 2);
                        st1[r] = (((pm1 >> c) & 1) && (c + 32 <= qr)) ? st1[r] : -INFINITY;
                    }
                }
            }

            // ---- online softmax, fully in-register ----
            float mloc = -INFINITY;
#pragma unroll
            for (int r = 0; r < 16; ++r) mloc = fmaxf(mloc, st0[r]);
            if (do2) {
#pragma unroll
                for (int r = 0; r < 16; ++r) mloc = fmaxf(mloc, st1[r]);
            }
            const float cmax = fmaxf(mloc, __shfl_xor(mloc, 32, 64));
            const float mnew = fmaxf(mrow, cmax);
            const float msafe = fmaxf(mnew, -1.0e30f);  // finite stand-in
            const float esc = __builtin_amdgcn_exp2f(mrow - msafe);  // -inf -> 0
#pragma unroll
            for (int r = 0; r < 16; ++r) { o0[r] *= esc; o1[r] *= esc; }
            lrow *= esc;
            mrow = mnew;

            // exponentials (masked -inf entries -> exp2(-inf) = 0; msafe finite)
            float tot = 0.f;
#pragma unroll
            for (int r = 0; r < 16; ++r) {
                st0[r] = __builtin_amdgcn_exp2f(st0[r] - msafe);
                tot += st0[r];
            }
            if (do2) {
#pragma unroll
                for (int r = 0; r < 16; ++r) {
                    st1[r] = __builtin_amdgcn_exp2f(st1[r] - msafe);
                    tot += st1[r];
                }
            }
            lrow += tot + __shfl_xor(tot, 32, 64);

            // ---- P -> bf16 B-fragments (pair redistribution via shfl) + PV ----
            __builtin_amdgcn_s_setprio(1);
#pragma unroll
            for (int kc = 0; kc < 2; ++kc) {
                uint32_t A0 = pk2bf(st0[kc * 8 + 0], st0[kc * 8 + 1]);
                uint32_t A1 = pk2bf(st0[kc * 8 + 2], st0[kc * 8 + 3]);
                uint32_t C0 = pk2bf(st0[kc * 8 + 4], st0[kc * 8 + 5]);
                uint32_t C1 = pk2bf(st0[kc * 8 + 6], st0[kc * 8 + 7]);
                uint32_t oA0 = __shfl_xor(A0, 32, 64), oA1 = __shfl_xor(A1, 32, 64);
                uint32_t oC0 = __shfl_xor(C0, 32, 64), oC1 = __shfl_xor(C1, 32, 64);
                i32x4 pf = {(int)(hi ? oC0 : A0), (int)(hi ? oC1 : A1),
                            (int)(hi ? C0 : oA0), (int)(hi ? C1 : oA1)};
                bf16x8 pb = *(bf16x8*)&pf;
                const int colb = kc * 32 + hi * 16;
                {
                    const int row = l31;
                    bf16x8 vf = *(const bf16x8*)(vbp + row * 128 + (colb ^ ((row & 7) << 4)));
                    o0 = __builtin_amdgcn_mfma_f32_32x32x16_bf16(vf, pb, o0, 0, 0, 0);
                }
                {
                    const int row = 32 + l31;
                    bf16x8 vf = *(const bf16x8*)(vbp + row * 128 + (colb ^ ((row & 7) << 4)));
                    o1 = __builtin_amdgcn_mfma_f32_32x32x16_bf16(vf, pb, o1, 0, 0, 0);
                }
            }
            if (do2) {
#pragma unroll
                for (int kc = 0; kc < 2; ++kc) {
                    uint32_t A0 = pk2bf(st1[kc * 8 + 0], st1[kc * 8 + 1]);
                    uint32_t A1 = pk2bf(st1[kc * 8 + 2], st1[kc * 8 + 3]);
                    uint32_t C0 = pk2bf(st1[kc * 8 + 4], st1[kc * 8 + 5]);
                    uint32_t C1 = pk2bf(st1[kc * 8 + 6], st1[kc * 8 + 7]);
                    uint32_t oA0 = __shfl_xor(A0, 32, 64), oA1 = __shfl_xor(A1, 32, 64);
                    uint32_t oC0 = __shfl_xor(C0, 32, 64), oC1 = __shfl_xor(C1, 32, 64);
                    i32x4 pf = {(int)(hi ? oC0 : A0), (int)(hi ? oC1 : A1),
                                (int)(hi ? C0 : oA0), (int)(hi ? C1 : oA1)};
                    bf16x8 pb = *(bf16x8*)&pf;
                    const int colb = (2 + kc) * 32 + hi * 16;
                    {
                        const int row = l31;
                        bf16x8 vf = *(const bf16x8*)(vbp + row * 128 + (colb ^ ((row & 7) << 4)));
                        o0 = __builtin_amdgcn_mfma_f32_32x32x16_bf16(vf, pb, o0, 0, 0, 0);
                    }
                    {
                        const int row = 32 + l31;
                        bf16x8 vf = *(const bf16x8*)(vbp + row * 128 + (colb ^ ((row & 7) << 4)));
                        o1 = __builtin_amdgcn_mfma_f32_32x32x16_bf16(vf, pb, o1, 0, 0, 0);
                    }
                }
            }
            __builtin_amdgcn_s_setprio(0);
        }
        BAR();
        cur ^= 1;
    }

    // ---- epilogue: normalize, write bf16 [b*T+q][h*64+d], 8B packed stores ----
    const float inv = (lrow > 0.f) ? (1.0f / lrow) : 0.f;
    unsigned short* orow = Og + ((size_t)(b * TT + q)) * DM + h * HD;
#pragma unroll
    for (int g4 = 0; g4 < 4; ++g4) {
        uint32_t w0 = pk2bf(o0[g4 * 4 + 0] * inv, o0[g4 * 4 + 1] * inv);
        uint32_t w1 = pk2bf(o0[g4 * 4 + 2] * inv, o0[g4 * 4 + 3] * inv);
        *(uint2*)(orow + g4 * 8 + 4 * hi) = make_uint2(w0, w1);
    }
#pragma unroll
    for (int g4 = 0; g4 < 4; ++g4) {
        uint32_t w0 = pk2bf(o1[g4 * 4 + 0] * inv, o1[g4 * 4 + 1] * inv);
        uint32_t w1 = pk2bf(o1[g4 * 4 + 2] * inv, o1[g4 * 4 + 3] * inv);
        *(uint2*)(orow + 32 + g4 * 8 + 4 * hi) = make_uint2(w0, w1);
    }
}

extern "C" void kernel_launch(void* const* d_in, const int* in_sizes, int n_in,
                              void* d_out, int out_size, void* d_ws, size_t ws_size,
                              hipStream_t stream) {
    const float* xq = (const float*)d_in[0];
    const float* xk = (const float*)d_in[1];
    const float* xv = (const float*)d_in[2];
    const int* pmask = (const int*)d_in[3];
    const float* Wq = (const float*)d_in[4];
    const float* bq = (const float*)d_in[5];
    const float* Wk = (const float*)d_in[6];
    const float* bk = (const float*)d_in[7];
    const float* Wv = (const float*)d_in[8];
    const float* bv = (const float*)d_in[9];
    const float* Wo = (const float*)d_in[10];
    const float* bo = (const float*)d_in[11];

    char* ws = (char*)d_ws;
    const size_t WT = (size_t)DM * DM * 2;             // 2 MB per transposed weight
    const size_t QKV = (size_t)NB * NH * TT * HD * 2;  // 16 MB each
    unsigned short* WqT = (unsigned short*)(ws + 0 * WT);
    unsigned short* WkT = (unsigned short*)(ws + 1 * WT);
    unsigned short* WvT = (unsigned short*)(ws + 2 * WT);
    unsigned short* WoT = (unsigned short*)(ws + 3 * WT);
    unsigned short* Qb = (unsigned short*)(ws + 4 * WT);
    unsigned short* Kb = (unsigned short*)(ws + 4 * WT + QKV);
    unsigned short* Vb = (unsigned short*)(ws + 4 * WT + 2 * QKV);
    unsigned short* Vt = (unsigned short*)(ws + 4 * WT + 3 * QKV);
    unsigned short* Xb = (unsigned short*)(ws + 4 * WT + 4 * QKV);  // reused x-bf16
    unsigned short* Ob = Vb;  // Vb dead after k_transpose_v; reuse for attn out

    dim3 tb(32, 8);
    k_transpose_w<<<dim3(32, 32), tb, 0, stream>>>(Wq, WqT);
    k_transpose_w<<<dim3(32, 32), tb, 0, stream>>>(Wk, WkT);
    k_transpose_w<<<dim3(32, 32), tb, 0, stream>>>(Wv, WvT);
    k_transpose_w<<<dim3(32, 32), tb, 0, stream>>>(Wo, WoT);

    const float qscale = 0.125f * 1.44269504088896340736f;  // 1/sqrt(64) * log2(e)
    const int n8 = NB * TT * DM / 8;
    dim3 gg(64, 8);  // M/128, N/128

    k_cvt_bf16<<<2048, 256, 0, stream>>>(xq, Xb, n8);
    k_gemm<0><<<gg, 256, 0, stream>>>(Xb, WqT, bq, Qb, qscale);
    k_cvt_bf16<<<2048, 256, 0, stream>>>(xk, Xb, n8);
    k_gemm<0><<<gg, 256, 0, stream>>>(Xb, WkT, bk, Kb, 1.0f);
    k_cvt_bf16<<<2048, 256, 0, stream>>>(xv, Xb, n8);
    k_gemm<0><<<gg, 256, 0, stream>>>(Xb, WvT, bv, Vb, 1.0f);

    k_transpose_v<<<dim3(TT / 32, HD / 32, NB * NH), tb, 0, stream>>>(Vb, Vt);

    k_attn<<<dim3(TT / QBLK, NB * NH), 512, 0, stream>>>(Qb, Kb, Vt, pmask, Ob);

    k_gemm<1><<<gg, 256, 0, stream>>>(Ob, WoT, bo, d_out, 1.0f);
}

// Round 9
// 249.809 us; speedup vs baseline: 1.2457x; 1.1014x over previous
//
#include <hip/hip_runtime.h>
#include <hip/hip_bf16.h>
#include <cstdint>

#define NB 4
#define TT 2048
#define DM 1024
#define NH 16
#define HD 64
#define QBLK 256
#define KVB 64

typedef __attribute__((ext_vector_type(8))) short bf16x8;
typedef __attribute__((ext_vector_type(4))) float f32x4;
typedef __attribute__((ext_vector_type(16))) float f32x16;
typedef __attribute__((ext_vector_type(4))) float float4v;
typedef __attribute__((ext_vector_type(4))) int i32x4;

static __device__ __forceinline__ unsigned short f2bf(float x) {
    unsigned int u = __float_as_uint(x);
    unsigned int r = (u + 0x7fffu + ((u >> 16) & 1u)) >> 16;
    return (unsigned short)r;
}
static __device__ __forceinline__ uint32_t pk2bf(float lo, float hi) {
    return (uint32_t)f2bf(lo) | ((uint32_t)f2bf(hi) << 16);
}

#define GLOAD16(gp, lp) __builtin_amdgcn_global_load_lds(                 \
    (const __attribute__((address_space(1))) void*)(gp),                  \
    (__attribute__((address_space(3))) void*)(lp), 16, 0, 0)
#define BAR() asm volatile("s_barrier" ::: "memory")
#define WAITV8() asm volatile("s_waitcnt vmcnt(8)" ::: "memory")
#define WAITV2() asm volatile("s_waitcnt vmcnt(2)" ::: "memory")
#define WAITV0() asm volatile("s_waitcnt vmcnt(0)" ::: "memory")

// ---- f32 -> bf16 bulk convert (8 elems/thread/iter) ----
__global__ __launch_bounds__(256) void k_cvt_bf16(const float* __restrict__ src,
                                                  unsigned short* __restrict__ dst,
                                                  int n8) {
    int i = blockIdx.x * 256 + threadIdx.x;
    const int stride = gridDim.x * 256;
    for (; i < n8; i += stride) {
        const float4v* s = (const float4v*)(src + (size_t)i * 8);
        float4v v0 = s[0], v1 = s[1];
        uint4 o;
        o.x = pk2bf(v0[0], v0[1]);
        o.y = pk2bf(v0[2], v0[3]);
        o.z = pk2bf(v1[0], v1[1]);
        o.w = pk2bf(v1[2], v1[3]);
        *(uint4*)(dst + (size_t)i * 8) = o;
    }
}

// ---- W[k][n] f32 -> Wt[n][k] bf16 (transpose + convert) ----
__global__ __launch_bounds__(256) void k_transpose_w(const float* __restrict__ W,
                                                     unsigned short* __restrict__ Wt) {
    __shared__ unsigned short tile[32][33];
    int tx = threadIdx.x, ty = threadIdx.y;
    int kb = blockIdx.x * 32, nb = blockIdx.y * 32;
#pragma unroll
    for (int i = 0; i < 4; ++i)
        tile[ty + i * 8][tx] = f2bf(W[(size_t)(kb + ty + i * 8) * DM + nb + tx]);
    __syncthreads();
#pragma unroll
    for (int i = 0; i < 4; ++i)
        Wt[(size_t)(nb + ty + i * 8) * DM + kb + tx] = tile[tx][ty + i * 8];
}

// ---- V[bh][t][d] bf16 -> Vt[bh][d][t] bf16 ----
__global__ __launch_bounds__(256) void k_transpose_v(const unsigned short* __restrict__ V,
                                                     unsigned short* __restrict__ Vt) {
    __shared__ unsigned short tile[32][34];
    int tx = threadIdx.x, ty = threadIdx.y;
    int bh = blockIdx.z;
    int t0 = blockIdx.x * 32, d0 = blockIdx.y * 32;
    const unsigned short* src = V + (size_t)bh * TT * HD;
    unsigned short* dst = Vt + (size_t)bh * HD * TT;
#pragma unroll
    for (int i = 0; i < 4; ++i)
        tile[ty + i * 8][tx] = src[(size_t)(t0 + ty + i * 8) * HD + d0 + tx];
    __syncthreads();
#pragma unroll
    for (int i = 0; i < 4; ++i)
        dst[(size_t)(d0 + ty + i * 8) * TT + t0 + tx] = tile[tx][ty + i * 8];
}

// ---- GEMM: C[8192][1024] = A_bf16[8192][1024] @ W[1024][1024] (+bias)*scale ----
// BK=64: 128B rows, XOR swizzle byte^=(row&7)<<4, global_load_lds(16B),
// raw-barrier double buffer, counted vmcnt(8). 16 K-iterations.
// OUT_MODE 0: scatter bf16 to [b,h,t,d]; 1: f32 row-major.
template <int OUT_MODE>
__global__ __launch_bounds__(256) void k_gemm(const unsigned short* __restrict__ A,
                                              const unsigned short* __restrict__ Bt,
                                              const float* __restrict__ bias,
                                              void* __restrict__ Cv, float scale) {
    __shared__ __align__(16) char Asl[2][16384];
    __shared__ __align__(16) char Bsl[2][16384];
    const int tid = threadIdx.x;
    const int lane = tid & 63, wid = tid >> 6;
    const int lg = lane >> 4, lc = lane & 15;
    const int wm = wid >> 1, wn = wid & 1;
    const int m0 = blockIdx.x * 128, n0 = blockIdx.y * 128;

    const char* Ab = (const char*)A;
    const char* Bb = (const char*)Bt;

    f32x4 acc[4][4];
#pragma unroll
    for (int mi = 0; mi < 4; ++mi)
#pragma unroll
        for (int ni = 0; ni < 4; ++ni)
            acc[mi][ni] = (f32x4){0.f, 0.f, 0.f, 0.f};

    auto stage = [&](int buf, int k0) {
#pragma unroll
        for (int j = 0; j < 4; ++j) {
            const int row = j * 32 + (tid >> 3);
            const int swz = ((tid & 7) * 16) ^ ((row & 7) << 4);
            GLOAD16(Ab + (size_t)(m0 + row) * (DM * 2) + k0 * 2 + swz,
                    &Asl[buf][0] + j * 4096 + tid * 16);
            GLOAD16(Bb + (size_t)(n0 + row) * (DM * 2) + k0 * 2 + swz,
                    &Bsl[buf][0] + j * 4096 + tid * 16);
        }
    };

    stage(0, 0);
    __syncthreads();  // drains vmcnt(0) for the prologue tile

    int cur = 0;
    for (int t = 0; t < DM / 64; ++t) {
        if (t + 1 < DM / 64) {
            stage(cur ^ 1, (t + 1) * 64);
            WAITV8();  // current tile's 8 loads done; next tile's 8 in flight
        } else {
            WAITV0();
        }
        BAR();

#pragma unroll
        for (int kk = 0; kk < 2; ++kk) {
            bf16x8 af[4], bfr[4];
#pragma unroll
            for (int ni = 0; ni < 4; ++ni) {
                const int n = wn * 64 + ni * 16 + lc;
                bfr[ni] = *(const bf16x8*)(&Bsl[cur][0] + n * 128 +
                                           ((kk * 64 + lg * 16) ^ ((n & 7) << 4)));
            }
#pragma unroll
            for (int mi = 0; mi < 4; ++mi) {
                const int m = wm * 64 + mi * 16 + lc;
                af[mi] = *(const bf16x8*)(&Asl[cur][0] + m * 128 +
                                          ((kk * 64 + lg * 16) ^ ((m & 7) << 4)));
            }
            __builtin_amdgcn_s_setprio(1);
#pragma unroll
            for (int mi = 0; mi < 4; ++mi)
#pragma unroll
                for (int ni = 0; ni < 4; ++ni)
                    acc[mi][ni] = __builtin_amdgcn_mfma_f32_16x16x32_bf16(af[mi], bfr[ni],
                                                                          acc[mi][ni], 0, 0, 0);
            __builtin_amdgcn_s_setprio(0);
        }
        BAR();
        cur ^= 1;
    }

#pragma unroll
    for (int mi = 0; mi < 4; ++mi)
#pragma unroll
        for (int ni = 0; ni < 4; ++ni)
#pragma unroll
            for (int r = 0; r < 4; ++r) {
                int m = m0 + wm * 64 + mi * 16 + lg * 4 + r;
                int n = n0 + wn * 64 + ni * 16 + lc;
                float val = (acc[mi][ni][r] + bias[n]) * scale;
                if (OUT_MODE == 0) {
                    int b = m >> 11, t = m & (TT - 1), h = n >> 6, d = n & 63;
                    ((unsigned short*)Cv)[(((size_t)b * NH + h) * TT + t) * HD + d] = f2bf(val);
                } else {
                    ((float*)Cv)[(size_t)m * DM + n] = val;
                }
            }
}

// ---- flash attention, swapped-QK^T 32x32 MFMA, in-register softmax ----
// 8 waves x 32 q-rows (QBLK=256). KV tiles of 64, double-buffered LDS in
// FRAGMENT ORDER: 16B chunk c of key/d-row r lives at (c*64+r)*16 — reads are
// chunk_base + l31*16 (conflict-free, no XOR). Staged by global_load_lds with
// per-lane global src (lane=row, wave=chunk), counted vmcnt(2).
// S^T = mfma(K, Q): col=lane&31=q, reg r holds key (r&3)+8*(r>>2)+4*(lane>>5).
__global__ __launch_bounds__(512) void k_attn(const unsigned short* __restrict__ Qg,
                                              const unsigned short* __restrict__ Kg,
                                              const unsigned short* __restrict__ Vtg,
                                              const int* __restrict__ pm,
                                              unsigned short* __restrict__ Og) {
    __shared__ __align__(16) unsigned short Kl[2][KVB * HD];  // 8 KB per buf
    __shared__ __align__(16) unsigned short Vl[2][KVB * HD];  // V^T tile, frag order
    __shared__ uint64_t pmbits[TT / 64];

    const int bh = blockIdx.y;
    const int b = bh >> 4, h = bh & 15;
    const int qb = gridDim.x - 1 - blockIdx.x;  // heavy blocks first
    const int qbase = qb * QBLK;
    const int tid = threadIdx.x;
    const int wid = tid >> 6, lane = tid & 63;
    const int hi = lane >> 5, l31 = lane & 31;
    const int q0 = qbase + wid * 32;
    const int q = q0 + l31;

    const unsigned short* Qh = Qg + (size_t)bh * TT * HD;
    const char* Khb = (const char*)(Kg + (size_t)bh * TT * HD);
    const char* Vthb = (const char*)(Vtg + (size_t)bh * HD * TT);
    const int* pmb = pm + b * TT;

    char* const kdst = (char*)&Kl[0][0];
    char* const vdst = (char*)&Vl[0][0];

    // prologue: stage tile 0 (drained by the __syncthreads below).
    // Wave wid stages chunk c=wid for all 64 rows: lane = key (K) / d (V).
    GLOAD16(Khb + (size_t)lane * 128 + wid * 16, kdst + tid * 16);
    GLOAD16(Vthb + (size_t)lane * 4096 + wid * 16, vdst + tid * 16);

    // padding-mask bitmasks (one u64 per 64-key tile); bit=1 -> key valid
#pragma unroll
    for (int it = 0; it < 4; ++it) {
        const int g = wid + it * 8;
        unsigned long long msk = __ballot(pmb[g * 64 + lane] != 0);
        if (lane == 0) pmbits[g] = msk;
    }

    // hoist Q fragments (B-operand: col q = lane&31, d-chunk dd*16 + hi*8)
    bf16x8 qf[4];
#pragma unroll
    for (int dd = 0; dd < 4; ++dd)
        qf[dd] = *(const bf16x8*)((const char*)Qh + (size_t)q * 128 + dd * 32 + hi * 16);

    f32x16 o0, o1;
#pragma unroll
    for (int r = 0; r < 16; ++r) { o0[r] = 0.f; o1[r] = 0.f; }
    float mrow = -INFINITY, msafe = -1.0e30f, lrow = 0.f;

    __syncthreads();  // pmbits visible; tile-0 loads drained (vmcnt 0)

    const int nt = (qbase + QBLK) >> 6;
    int cur = 0;
    for (int t = 0; t < nt; ++t) {
        const int kv0 = t << 6;
        if (t + 1 < nt) {
            const int kn = kv0 + KVB;
            const int nb = (cur ^ 1) * 8192 + tid * 16;
            GLOAD16(Khb + (size_t)(kn + lane) * 128 + wid * 16, kdst + nb);
            GLOAD16(Vthb + (size_t)lane * 4096 + (size_t)kn * 2 + wid * 16, vdst + nb);
            WAITV2();  // current tile's 2 loads done; next tile's 2 in flight
        } else {
            WAITV0();
        }
        BAR();

        if (kv0 <= q0 + 31) {  // wave-uniform causal skip
            const uint64_t vb = pmbits[kv0 >> 6];
            const uint32_t pm0 = ((uint32_t)vb) >> (4 * hi);
            const uint32_t pm1 = ((uint32_t)(vb >> 32)) >> (4 * hi);
            const bool allvalid = (vb == ~0ull);
            const bool do2 = (kv0 + 32 <= q0 + 31);
            const bool needmask = (kv0 + 63 > q0) || !allvalid;
            const char* kb = (const char*)&Kl[0][0] + cur * 8192;
            const char* vbp = (const char*)&Vl[0][0] + cur * 8192;

            // ---- QK^T: S^T[key][q] ----
            f32x16 st0, st1;
#pragma unroll
            for (int r = 0; r < 16; ++r) { st0[r] = 0.f; st1[r] = 0.f; }
            __builtin_amdgcn_s_setprio(1);
#pragma unroll
            for (int dd = 0; dd < 4; ++dd) {
                const char* kchunk = kb + (dd * 2 + hi) * 1024;
                bf16x8 kf = *(const bf16x8*)(kchunk + l31 * 16);
                st0 = __builtin_amdgcn_mfma_f32_32x32x16_bf16(kf, qf[dd], st0, 0, 0, 0);
            }
            if (do2) {
#pragma unroll
                for (int dd = 0; dd < 4; ++dd) {
                    const char* kchunk = kb + (dd * 2 + hi) * 1024;
                    bf16x8 kf = *(const bf16x8*)(kchunk + 512 + l31 * 16);
                    st1 = __builtin_amdgcn_mfma_f32_32x32x16_bf16(kf, qf[dd], st1, 0, 0, 0);
                }
            }
            __builtin_amdgcn_s_setprio(0);

            // ---- masking (causal + padding), lane-local ----
            const int qr = q - kv0 - 4 * hi;
            if (needmask) {
#pragma unroll
                for (int r = 0; r < 16; ++r) {
                    const int c = (r & 3) + 8 * (r >> 2);
                    st0[r] = (((pm0 >> c) & 1) && (c <= qr)) ? st0[r] : -INFINITY;
                }
                if (do2) {
#pragma unroll
                    for (int r = 0; r < 16; ++r) {
                        const int c = (r & 3) + 8 * (r >> 2);
                        st1[r] = (((pm1 >> c) & 1) && (c + 32 <= qr)) ? st1[r] : -INFINITY;
                    }
                }
            }

            // ---- online softmax, in-register, defer-max (T13) ----
            float mloc = -INFINITY;
#pragma unroll
            for (int r = 0; r < 16; ++r) mloc = fmaxf(mloc, st0[r]);
            if (do2) {
#pragma unroll
                for (int r = 0; r < 16; ++r) mloc = fmaxf(mloc, st1[r]);
            }
            const float cmax = fmaxf(mloc, __shfl_xor(mloc, 32, 64));
            // rescale only when max moved >8 (exp2 domain); invariant
            // msafe == max(mrow, -1e30) holds (deferral updates neither).
            if (!__all(cmax - mrow <= 8.0f)) {
                const float mnew = fmaxf(mrow, cmax);
                const float ms = fmaxf(mnew, -1.0e30f);
                const float esc = __builtin_amdgcn_exp2f(mrow - ms);  // -inf -> 0
#pragma unroll
                for (int r = 0; r < 16; ++r) { o0[r] *= esc; o1[r] *= esc; }
                lrow *= esc;
                mrow = mnew;
                msafe = ms;
            }

            // exponentials vs finite msafe (masked -inf -> 0; bounded by 2^8)
            float tot = 0.f;
#pragma unroll
            for (int r = 0; r < 16; ++r) {
                st0[r] = __builtin_amdgcn_exp2f(st0[r] - msafe);
                tot += st0[r];
            }
            if (do2) {
#pragma unroll
                for (int r = 0; r < 16; ++r) {
                    st1[r] = __builtin_amdgcn_exp2f(st1[r] - msafe);
                    tot += st1[r];
                }
            }
            lrow += tot + __shfl_xor(tot, 32, 64);

            // ---- P -> bf16 B-fragments (pair redistribution via shfl) + PV ----
            __builtin_amdgcn_s_setprio(1);
#pragma unroll
            for (int kc = 0; kc < 2; ++kc) {
                uint32_t A0 = pk2bf(st0[kc * 8 + 0], st0[kc * 8 + 1]);
                uint32_t A1 = pk2bf(st0[kc * 8 + 2], st0[kc * 8 + 3]);
                uint32_t C0 = pk2bf(st0[kc * 8 + 4], st0[kc * 8 + 5]);
                uint32_t C1 = pk2bf(st0[kc * 8 + 6], st0[kc * 8 + 7]);
                uint32_t oA0 = __shfl_xor(A0, 32, 64), oA1 = __shfl_xor(A1, 32, 64);
                uint32_t oC0 = __shfl_xor(C0, 32, 64), oC1 = __shfl_xor(C1, 32, 64);
                i32x4 pf = {(int)(hi ? oC0 : A0), (int)(hi ? oC1 : A1),
                            (int)(hi ? C0 : oA0), (int)(hi ? C1 : oA1)};
                bf16x8 pb = *(bf16x8*)&pf;
                const char* vchunk = vbp + (kc * 2 + hi) * 1024;
                {
                    bf16x8 vf = *(const bf16x8*)(vchunk + l31 * 16);
                    o0 = __builtin_amdgcn_mfma_f32_32x32x16_bf16(vf, pb, o0, 0, 0, 0);
                }
                {
                    bf16x8 vf = *(const bf16x8*)(vchunk + 512 + l31 * 16);
                    o1 = __builtin_amdgcn_mfma_f32_32x32x16_bf16(vf, pb, o1, 0, 0, 0);
                }
            }
            if (do2) {
#pragma unroll
                for (int kc = 0; kc < 2; ++kc) {
                    uint32_t A0 = pk2bf(st1[kc * 8 + 0], st1[kc * 8 + 1]);
                    uint32_t A1 = pk2bf(st1[kc * 8 + 2], st1[kc * 8 + 3]);
                    uint32_t C0 = pk2bf(st1[kc * 8 + 4], st1[kc * 8 + 5]);
                    uint32_t C1 = pk2bf(st1[kc * 8 + 6], st1[kc * 8 + 7]);
                    uint32_t oA0 = __shfl_xor(A0, 32, 64), oA1 = __shfl_xor(A1, 32, 64);
                    uint32_t oC0 = __shfl_xor(C0, 32, 64), oC1 = __shfl_xor(C1, 32, 64);
                    i32x4 pf = {(int)(hi ? oC0 : A0), (int)(hi ? oC1 : A1),
                                (int)(hi ? C0 : oA0), (int)(hi ? C1 : oA1)};
                    bf16x8 pb = *(bf16x8*)&pf;
                    const char* vchunk = vbp + (4 + kc * 2 + hi) * 1024;
                    {
                        bf16x8 vf = *(const bf16x8*)(vchunk + l31 * 16);
                        o0 = __builtin_amdgcn_mfma_f32_32x32x16_bf16(vf, pb, o0, 0, 0, 0);
                    }
                    {
                        bf16x8 vf = *(const bf16x8*)(vchunk + 512 + l31 * 16);
                        o1 = __builtin_amdgcn_mfma_f32_32x32x16_bf16(vf, pb, o1, 0, 0, 0);
                    }
                }
            }
            __builtin_amdgcn_s_setprio(0);
        }
        BAR();
        cur ^= 1;
    }

    // ---- epilogue: normalize, write bf16 [b*T+q][h*64+d], 8B packed stores ----
    const float inv = (lrow > 0.f) ? (1.0f / lrow) : 0.f;
    unsigned short* orow = Og + ((size_t)(b * TT + q)) * DM + h * HD;
#pragma unroll
    for (int g4 = 0; g4 < 4; ++g4) {
        uint32_t w0 = pk2bf(o0[g4 * 4 + 0] * inv, o0[g4 * 4 + 1] * inv);
        uint32_t w1 = pk2bf(o0[g4 * 4 + 2] * inv, o0[g4 * 4 + 3] * inv);
        *(uint2*)(orow + g4 * 8 + 4 * hi) = make_uint2(w0, w1);
    }
#pragma unroll
    for (int g4 = 0; g4 < 4; ++g4) {
        uint32_t w0 = pk2bf(o1[g4 * 4 + 0] * inv, o1[g4 * 4 + 1] * inv);
        uint32_t w1 = pk2bf(o1[g4 * 4 + 2] * inv, o1[g4 * 4 + 3] * inv);
        *(uint2*)(orow + 32 + g4 * 8 + 4 * hi) = make_uint2(w0, w1);
    }
}

extern "C" void kernel_launch(void* const* d_in, const int* in_sizes, int n_in,
                              void* d_out, int out_size, void* d_ws, size_t ws_size,
                              hipStream_t stream) {
    const float* xq = (const float*)d_in[0];
    const float* xk = (const float*)d_in[1];
    const float* xv = (const float*)d_in[2];
    const int* pmask = (const int*)d_in[3];
    const float* Wq = (const float*)d_in[4];
    const float* bq = (const float*)d_in[5];
    const float* Wk = (const float*)d_in[6];
    const float* bk = (const float*)d_in[7];
    const float* Wv = (const float*)d_in[8];
    const float* bv = (const float*)d_in[9];
    const float* Wo = (const float*)d_in[10];
    const float* bo = (const float*)d_in[11];

    char* ws = (char*)d_ws;
    const size_t WT = (size_t)DM * DM * 2;             // 2 MB per transposed weight
    const size_t QKV = (size_t)NB * NH * TT * HD * 2;  // 16 MB each
    unsigned short* WqT = (unsigned short*)(ws + 0 * WT);
    unsigned short* WkT = (unsigned short*)(ws + 1 * WT);
    unsigned short* WvT = (unsigned short*)(ws + 2 * WT);
    unsigned short* WoT = (unsigned short*)(ws + 3 * WT);
    unsigned short* Qb = (unsigned short*)(ws + 4 * WT);
    unsigned short* Kb = (unsigned short*)(ws + 4 * WT + QKV);
    unsigned short* Vb = (unsigned short*)(ws + 4 * WT + 2 * QKV);
    unsigned short* Vt = (unsigned short*)(ws + 4 * WT + 3 * QKV);
    unsigned short* Xb = (unsigned short*)(ws + 4 * WT + 4 * QKV);  // reused x-bf16
    unsigned short* Ob = Vb;  // Vb dead after k_transpose_v; reuse for attn out

    dim3 tb(32, 8);
    k_transpose_w<<<dim3(32, 32), tb, 0, stream>>>(Wq, WqT);
    k_transpose_w<<<dim3(32, 32), tb, 0, stream>>>(Wk, WkT);
    k_transpose_w<<<dim3(32, 32), tb, 0, stream>>>(Wv, WvT);
    k_transpose_w<<<dim3(32, 32), tb, 0, stream>>>(Wo, WoT);

    const float qscale = 0.125f * 1.44269504088896340736f;  // 1/sqrt(64) * log2(e)
    const int n8 = NB * TT * DM / 8;
    dim3 gg(64, 8);  // M/128, N/128

    k_cvt_bf16<<<2048, 256, 0, stream>>>(xq, Xb, n8);
    k_gemm<0><<<gg, 256, 0, stream>>>(Xb, WqT, bq, Qb, qscale);
    k_cvt_bf16<<<2048, 256, 0, stream>>>(xk, Xb, n8);
    k_gemm<0><<<gg, 256, 0, stream>>>(Xb, WkT, bk, Kb, 1.0f);
    k_cvt_bf16<<<2048, 256, 0, stream>>>(xv, Xb, n8);
    k_gemm<0><<<gg, 256, 0, stream>>>(Xb, WvT, bv, Vb, 1.0f);

    k_transpose_v<<<dim3(TT / 32, HD / 32, NB * NH), tb, 0, stream>>>(Vb, Vt);

    k_attn<<<dim3(TT / QBLK, NB * NH), 512, 0, stream>>>(Qb, Kb, Vt, pmask, Ob);

    k_gemm<1><<<gg, 256, 0, stream>>>(Ob, WoT, bo, d_out, 1.0f);
}

// Round 10
// 242.922 us; speedup vs baseline: 1.2810x; 1.0283x over previous
//
#include <hip/hip_runtime.h>
#include <hip/hip_bf16.h>
#include <cstdint>

#define NB 4
#define TT 2048
#define DM 1024
#define NH 16
#define HD 64
#define QBLK 256
#define KVB 64

typedef __attribute__((ext_vector_type(8))) short bf16x8;
typedef __attribute__((ext_vector_type(4))) float f32x4;
typedef __attribute__((ext_vector_type(16))) float f32x16;
typedef __attribute__((ext_vector_type(4))) float float4v;
typedef __attribute__((ext_vector_type(4))) int i32x4;

static __device__ __forceinline__ unsigned short f2bf(float x) {
    unsigned int u = __float_as_uint(x);
    unsigned int r = (u + 0x7fffu + ((u >> 16) & 1u)) >> 16;
    return (unsigned short)r;
}
static __device__ __forceinline__ uint32_t pk2bf(float lo, float hi) {
    return (uint32_t)f2bf(lo) | ((uint32_t)f2bf(hi) << 16);
}

#define GLOAD16(gp, lp) __builtin_amdgcn_global_load_lds(                 \
    (const __attribute__((address_space(1))) void*)(gp),                  \
    (__attribute__((address_space(3))) void*)(lp), 16, 0, 0)
#define BAR() asm volatile("s_barrier" ::: "memory")
#define WAITV8() asm volatile("s_waitcnt vmcnt(8)" ::: "memory")
#define WAITV2() asm volatile("s_waitcnt vmcnt(2)" ::: "memory")
#define WAITV0() asm volatile("s_waitcnt vmcnt(0)" ::: "memory")

// ---- f32 -> bf16 bulk convert (8 elems/thread/iter) ----
__global__ __launch_bounds__(256) void k_cvt_bf16(const float* __restrict__ src,
                                                  unsigned short* __restrict__ dst,
                                                  int n8) {
    int i = blockIdx.x * 256 + threadIdx.x;
    const int stride = gridDim.x * 256;
    for (; i < n8; i += stride) {
        const float4v* s = (const float4v*)(src + (size_t)i * 8);
        float4v v0 = s[0], v1 = s[1];
        uint4 o;
        o.x = pk2bf(v0[0], v0[1]);
        o.y = pk2bf(v0[2], v0[3]);
        o.z = pk2bf(v1[0], v1[1]);
        o.w = pk2bf(v1[2], v1[3]);
        *(uint4*)(dst + (size_t)i * 8) = o;
    }
}

// ---- W[k][n] f32 -> Wt[n][k] bf16 (transpose + convert) ----
__global__ __launch_bounds__(256) void k_transpose_w(const float* __restrict__ W,
                                                     unsigned short* __restrict__ Wt) {
    __shared__ unsigned short tile[32][33];
    int tx = threadIdx.x, ty = threadIdx.y;
    int kb = blockIdx.x * 32, nb = blockIdx.y * 32;
#pragma unroll
    for (int i = 0; i < 4; ++i)
        tile[ty + i * 8][tx] = f2bf(W[(size_t)(kb + ty + i * 8) * DM + nb + tx]);
    __syncthreads();
#pragma unroll
    for (int i = 0; i < 4; ++i)
        Wt[(size_t)(nb + ty + i * 8) * DM + kb + tx] = tile[tx][ty + i * 8];
}

// ---- V[bh][t][d] bf16 -> Vt[bh][d][t] bf16 ----
__global__ __launch_bounds__(256) void k_transpose_v(const unsigned short* __restrict__ V,
                                                     unsigned short* __restrict__ Vt) {
    __shared__ unsigned short tile[32][34];
    int tx = threadIdx.x, ty = threadIdx.y;
    int bh = blockIdx.z;
    int t0 = blockIdx.x * 32, d0 = blockIdx.y * 32;
    const unsigned short* src = V + (size_t)bh * TT * HD;
    unsigned short* dst = Vt + (size_t)bh * HD * TT;
#pragma unroll
    for (int i = 0; i < 4; ++i)
        tile[ty + i * 8][tx] = src[(size_t)(t0 + ty + i * 8) * HD + d0 + tx];
    __syncthreads();
#pragma unroll
    for (int i = 0; i < 4; ++i)
        dst[(size_t)(d0 + ty + i * 8) * TT + t0 + tx] = tile[tx][ty + i * 8];
}

// ---- GEMM: C[8192][1024] = A_bf16[8192][1024] @ W[1024][1024] (+bias)*scale ----
// BK=64: 128B rows, XOR swizzle byte^=(row&7)<<4, global_load_lds(16B),
// raw-barrier double buffer, counted vmcnt(8). 16 K-iterations.
// OUT_MODE 0: scatter bf16 to [b,h,t,d]; 1: f32 row-major.
template <int OUT_MODE>
__global__ __launch_bounds__(256) void k_gemm(const unsigned short* __restrict__ A,
                                              const unsigned short* __restrict__ Bt,
                                              const float* __restrict__ bias,
                                              void* __restrict__ Cv, float scale) {
    __shared__ __align__(16) char Asl[2][16384];
    __shared__ __align__(16) char Bsl[2][16384];
    const int tid = threadIdx.x;
    const int lane = tid & 63, wid = tid >> 6;
    const int lg = lane >> 4, lc = lane & 15;
    const int wm = wid >> 1, wn = wid & 1;
    const int m0 = blockIdx.x * 128, n0 = blockIdx.y * 128;

    const char* Ab = (const char*)A;
    const char* Bb = (const char*)Bt;

    f32x4 acc[4][4];
#pragma unroll
    for (int mi = 0; mi < 4; ++mi)
#pragma unroll
        for (int ni = 0; ni < 4; ++ni)
            acc[mi][ni] = (f32x4){0.f, 0.f, 0.f, 0.f};

    auto stage = [&](int buf, int k0) {
#pragma unroll
        for (int j = 0; j < 4; ++j) {
            const int row = j * 32 + (tid >> 3);
            const int swz = ((tid & 7) * 16) ^ ((row & 7) << 4);
            GLOAD16(Ab + (size_t)(m0 + row) * (DM * 2) + k0 * 2 + swz,
                    &Asl[buf][0] + j * 4096 + tid * 16);
            GLOAD16(Bb + (size_t)(n0 + row) * (DM * 2) + k0 * 2 + swz,
                    &Bsl[buf][0] + j * 4096 + tid * 16);
        }
    };

    stage(0, 0);
    __syncthreads();  // drains vmcnt(0) for the prologue tile

    int cur = 0;
    for (int t = 0; t < DM / 64; ++t) {
        if (t + 1 < DM / 64) {
            stage(cur ^ 1, (t + 1) * 64);
            WAITV8();  // current tile's 8 loads done; next tile's 8 in flight
        } else {
            WAITV0();
        }
        BAR();

#pragma unroll
        for (int kk = 0; kk < 2; ++kk) {
            bf16x8 af[4], bfr[4];
#pragma unroll
            for (int ni = 0; ni < 4; ++ni) {
                const int n = wn * 64 + ni * 16 + lc;
                bfr[ni] = *(const bf16x8*)(&Bsl[cur][0] + n * 128 +
                                           ((kk * 64 + lg * 16) ^ ((n & 7) << 4)));
            }
#pragma unroll
            for (int mi = 0; mi < 4; ++mi) {
                const int m = wm * 64 + mi * 16 + lc;
                af[mi] = *(const bf16x8*)(&Asl[cur][0] + m * 128 +
                                          ((kk * 64 + lg * 16) ^ ((m & 7) << 4)));
            }
            __builtin_amdgcn_s_setprio(1);
#pragma unroll
            for (int mi = 0; mi < 4; ++mi)
#pragma unroll
                for (int ni = 0; ni < 4; ++ni)
                    acc[mi][ni] = __builtin_amdgcn_mfma_f32_16x16x32_bf16(af[mi], bfr[ni],
                                                                          acc[mi][ni], 0, 0, 0);
            __builtin_amdgcn_s_setprio(0);
        }
        BAR();
        cur ^= 1;
    }

#pragma unroll
    for (int mi = 0; mi < 4; ++mi)
#pragma unroll
        for (int ni = 0; ni < 4; ++ni)
#pragma unroll
            for (int r = 0; r < 4; ++r) {
                int m = m0 + wm * 64 + mi * 16 + lg * 4 + r;
                int n = n0 + wn * 64 + ni * 16 + lc;
                float val = (acc[mi][ni][r] + bias[n]) * scale;
                if (OUT_MODE == 0) {
                    int b = m >> 11, t = m & (TT - 1), h = n >> 6, d = n & 63;
                    ((unsigned short*)Cv)[(((size_t)b * NH + h) * TT + t) * HD + d] = f2bf(val);
                } else {
                    ((float*)Cv)[(size_t)m * DM + n] = val;
                }
            }
}

// ---- flash attention, swapped-QK^T 32x32 MFMA, in-register softmax ----
// 8 waves x 32 q-rows (QBLK=256). KV tiles of 64, double-buffered LDS in
// fragment order (16B chunk c of row r at (c*64+r)*16 — conflict-free reads).
// 1-D grid of 512: adjacent blocks get complementary causal loads (qb, 7-qb)
// and the same head (L2 K/V reuse) -> per-CU tile count ~constant (36).
// S^T = mfma(K, Q): col=lane&31=q, reg r holds key (r&3)+8*(r>>2)+4*(lane>>5).
__global__ __launch_bounds__(512) void k_attn(const unsigned short* __restrict__ Qg,
                                              const unsigned short* __restrict__ Kg,
                                              const unsigned short* __restrict__ Vtg,
                                              const int* __restrict__ pm,
                                              unsigned short* __restrict__ Og) {
    __shared__ __align__(16) unsigned short Kl[2][KVB * HD];  // 8 KB per buf
    __shared__ __align__(16) unsigned short Vl[2][KVB * HD];  // V^T tile, frag order
    __shared__ uint64_t pmbits[TT / 64];

    // balanced (qb, bh) mapping: pair p -> {a, 7-a}, same bh for the pair
    const int idx = blockIdx.x;
    const int p = idx >> 1, s = idx & 1;
    const int a = p & 3;
    const int qb = s ? (7 - a) : a;
    const int bh = p >> 2;
    const int b = bh >> 4, h = bh & 15;
    const int qbase = qb * QBLK;
    const int tid = threadIdx.x;
    const int wid = tid >> 6, lane = tid & 63;
    const int hi = lane >> 5, l31 = lane & 31;
    const int q0 = qbase + wid * 32;
    const int q = q0 + l31;

    const unsigned short* Qh = Qg + (size_t)bh * TT * HD;
    const char* Khb = (const char*)(Kg + (size_t)bh * TT * HD);
    const char* Vthb = (const char*)(Vtg + (size_t)bh * HD * TT);
    const int* pmb = pm + b * TT;

    char* const kdst = (char*)&Kl[0][0];
    char* const vdst = (char*)&Vl[0][0];

    // prologue: stage tile 0 (drained by the __syncthreads below).
    // Wave wid stages chunk c=wid for all 64 rows: lane = key (K) / d (V).
    GLOAD16(Khb + (size_t)lane * 128 + wid * 16, kdst + tid * 16);
    GLOAD16(Vthb + (size_t)lane * 4096 + wid * 16, vdst + tid * 16);

    // padding-mask bitmasks (one u64 per 64-key tile); bit=1 -> key valid
#pragma unroll
    for (int it = 0; it < 4; ++it) {
        const int g = wid + it * 8;
        unsigned long long msk = __ballot(pmb[g * 64 + lane] != 0);
        if (lane == 0) pmbits[g] = msk;
    }

    // hoist Q fragments (B-operand: col q = lane&31, d-chunk dd*16 + hi*8)
    bf16x8 qf[4];
#pragma unroll
    for (int dd = 0; dd < 4; ++dd)
        qf[dd] = *(const bf16x8*)((const char*)Qh + (size_t)q * 128 + dd * 32 + hi * 16);

    f32x16 o0, o1;
#pragma unroll
    for (int r = 0; r < 16; ++r) { o0[r] = 0.f; o1[r] = 0.f; }
    float mrow = -INFINITY, msafe = -1.0e30f, lrow = 0.f;

    __syncthreads();  // pmbits visible; tile-0 loads drained (vmcnt 0)

    const int nt = (qbase + QBLK) >> 6;
    int cur = 0;
    for (int t = 0; t < nt; ++t) {
        const int kv0 = t << 6;
        if (t + 1 < nt) {
            const int kn = kv0 + KVB;
            const int nb = (cur ^ 1) * 8192 + tid * 16;
            GLOAD16(Khb + (size_t)(kn + lane) * 128 + wid * 16, kdst + nb);
            GLOAD16(Vthb + (size_t)lane * 4096 + (size_t)kn * 2 + wid * 16, vdst + nb);
            WAITV2();  // current tile's 2 loads done; next tile's 2 in flight
        } else {
            WAITV0();
        }
        BAR();

        if (kv0 <= q0 + 31) {  // wave-uniform causal skip
            const uint64_t vb = pmbits[kv0 >> 6];
            const uint32_t pm0 = ((uint32_t)vb) >> (4 * hi);
            const uint32_t pm1 = ((uint32_t)(vb >> 32)) >> (4 * hi);
            const bool allvalid = (vb == ~0ull);
            const bool do2 = (kv0 + 32 <= q0 + 31);
            const bool needmask = (kv0 + 63 > q0) || !allvalid;
            const char* kb = (const char*)&Kl[0][0] + cur * 8192;
            const char* vbp = (const char*)&Vl[0][0] + cur * 8192;

            // ---- QK^T: S^T[key][q] ----
            f32x16 st0, st1;
#pragma unroll
            for (int r = 0; r < 16; ++r) { st0[r] = 0.f; st1[r] = 0.f; }
            __builtin_amdgcn_s_setprio(1);
#pragma unroll
            for (int dd = 0; dd < 4; ++dd) {
                const char* kchunk = kb + (dd * 2 + hi) * 1024;
                bf16x8 kf = *(const bf16x8*)(kchunk + l31 * 16);
                st0 = __builtin_amdgcn_mfma_f32_32x32x16_bf16(kf, qf[dd], st0, 0, 0, 0);
            }
            if (do2) {
#pragma unroll
                for (int dd = 0; dd < 4; ++dd) {
                    const char* kchunk = kb + (dd * 2 + hi) * 1024;
                    bf16x8 kf = *(const bf16x8*)(kchunk + 512 + l31 * 16);
                    st1 = __builtin_amdgcn_mfma_f32_32x32x16_bf16(kf, qf[dd], st1, 0, 0, 0);
                }
            }
            __builtin_amdgcn_s_setprio(0);

            // ---- masking (causal + padding), lane-local ----
            const int qr = q - kv0 - 4 * hi;
            if (needmask) {
#pragma unroll
                for (int r = 0; r < 16; ++r) {
                    const int c = (r & 3) + 8 * (r >> 2);
                    st0[r] = (((pm0 >> c) & 1) && (c <= qr)) ? st0[r] : -INFINITY;
                }
                if (do2) {
#pragma unroll
                    for (int r = 0; r < 16; ++r) {
                        const int c = (r & 3) + 8 * (r >> 2);
                        st1[r] = (((pm1 >> c) & 1) && (c + 32 <= qr)) ? st1[r] : -INFINITY;
                    }
                }
            }

            // ---- online softmax, in-register, defer-max (T13) ----
            float mloc = -INFINITY;
#pragma unroll
            for (int r = 0; r < 16; ++r) mloc = fmaxf(mloc, st0[r]);
            if (do2) {
#pragma unroll
                for (int r = 0; r < 16; ++r) mloc = fmaxf(mloc, st1[r]);
            }
            const float cmax = fmaxf(mloc, __shfl_xor(mloc, 32, 64));
            // rescale only when max moved >8 (exp2 domain); invariant
            // msafe == max(mrow, -1e30) holds (deferral updates neither).
            if (!__all(cmax - mrow <= 8.0f)) {
                const float mnew = fmaxf(mrow, cmax);
                const float ms = fmaxf(mnew, -1.0e30f);
                const float esc = __builtin_amdgcn_exp2f(mrow - ms);  // -inf -> 0
#pragma unroll
                for (int r = 0; r < 16; ++r) { o0[r] *= esc; o1[r] *= esc; }
                lrow *= esc;
                mrow = mnew;
                msafe = ms;
            }

            // exponentials vs finite msafe (masked -inf -> 0; bounded by 2^8)
            float tot = 0.f;
#pragma unroll
            for (int r = 0; r < 16; ++r) {
                st0[r] = __builtin_amdgcn_exp2f(st0[r] - msafe);
                tot += st0[r];
            }
            if (do2) {
#pragma unroll
                for (int r = 0; r < 16; ++r) {
                    st1[r] = __builtin_amdgcn_exp2f(st1[r] - msafe);
                    tot += st1[r];
                }
            }
            lrow += tot + __shfl_xor(tot, 32, 64);

            // ---- P -> bf16 B-fragments (pair redistribution via shfl) + PV ----
            __builtin_amdgcn_s_setprio(1);
#pragma unroll
            for (int kc = 0; kc < 2; ++kc) {
                uint32_t A0 = pk2bf(st0[kc * 8 + 0], st0[kc * 8 + 1]);
                uint32_t A1 = pk2bf(st0[kc * 8 + 2], st0[kc * 8 + 3]);
                uint32_t C0 = pk2bf(st0[kc * 8 + 4], st0[kc * 8 + 5]);
                uint32_t C1 = pk2bf(st0[kc * 8 + 6], st0[kc * 8 + 7]);
                uint32_t oA0 = __shfl_xor(A0, 32, 64), oA1 = __shfl_xor(A1, 32, 64);
                uint32_t oC0 = __shfl_xor(C0, 32, 64), oC1 = __shfl_xor(C1, 32, 64);
                i32x4 pf = {(int)(hi ? oC0 : A0), (int)(hi ? oC1 : A1),
                            (int)(hi ? C0 : oA0), (int)(hi ? C1 : oA1)};
                bf16x8 pb = *(bf16x8*)&pf;
                const char* vchunk = vbp + (kc * 2 + hi) * 1024;
                {
                    bf16x8 vf = *(const bf16x8*)(vchunk + l31 * 16);
                    o0 = __builtin_amdgcn_mfma_f32_32x32x16_bf16(vf, pb, o0, 0, 0, 0);
                }
                {
                    bf16x8 vf = *(const bf16x8*)(vchunk + 512 + l31 * 16);
                    o1 = __builtin_amdgcn_mfma_f32_32x32x16_bf16(vf, pb, o1, 0, 0, 0);
                }
            }
            if (do2) {
#pragma unroll
                for (int kc = 0; kc < 2; ++kc) {
                    uint32_t A0 = pk2bf(st1[kc * 8 + 0], st1[kc * 8 + 1]);
                    uint32_t A1 = pk2bf(st1[kc * 8 + 2], st1[kc * 8 + 3]);
                    uint32_t C0 = pk2bf(st1[kc * 8 + 4], st1[kc * 8 + 5]);
                    uint32_t C1 = pk2bf(st1[kc * 8 + 6], st1[kc * 8 + 7]);
                    uint32_t oA0 = __shfl_xor(A0, 32, 64), oA1 = __shfl_xor(A1, 32, 64);
                    uint32_t oC0 = __shfl_xor(C0, 32, 64), oC1 = __shfl_xor(C1, 32, 64);
                    i32x4 pf = {(int)(hi ? oC0 : A0), (int)(hi ? oC1 : A1),
                                (int)(hi ? C0 : oA0), (int)(hi ? C1 : oA1)};
                    bf16x8 pb = *(bf16x8*)&pf;
                    const char* vchunk = vbp + (4 + kc * 2 + hi) * 1024;
                    {
                        bf16x8 vf = *(const bf16x8*)(vchunk + l31 * 16);
                        o0 = __builtin_amdgcn_mfma_f32_32x32x16_bf16(vf, pb, o0, 0, 0, 0);
                    }
                    {
                        bf16x8 vf = *(const bf16x8*)(vchunk + 512 + l31 * 16);
                        o1 = __builtin_amdgcn_mfma_f32_32x32x16_bf16(vf, pb, o1, 0, 0, 0);
                    }
                }
            }
            __builtin_amdgcn_s_setprio(0);
        }
        BAR();
        cur ^= 1;
    }

    // ---- epilogue: normalize, write bf16 [b*T+q][h*64+d], 8B packed stores ----
    const float inv = (lrow > 0.f) ? (1.0f / lrow) : 0.f;
    unsigned short* orow = Og + ((size_t)(b * TT + q)) * DM + h * HD;
#pragma unroll
    for (int g4 = 0; g4 < 4; ++g4) {
        uint32_t w0 = pk2bf(o0[g4 * 4 + 0] * inv, o0[g4 * 4 + 1] * inv);
        uint32_t w1 = pk2bf(o0[g4 * 4 + 2] * inv, o0[g4 * 4 + 3] * inv);
        *(uint2*)(orow + g4 * 8 + 4 * hi) = make_uint2(w0, w1);
    }
#pragma unroll
    for (int g4 = 0; g4 < 4; ++g4) {
        uint32_t w0 = pk2bf(o1[g4 * 4 + 0] * inv, o1[g4 * 4 + 1] * inv);
        uint32_t w1 = pk2bf(o1[g4 * 4 + 2] * inv, o1[g4 * 4 + 3] * inv);
        *(uint2*)(orow + 32 + g4 * 8 + 4 * hi) = make_uint2(w0, w1);
    }
}

extern "C" void kernel_launch(void* const* d_in, const int* in_sizes, int n_in,
                              void* d_out, int out_size, void* d_ws, size_t ws_size,
                              hipStream_t stream) {
    const float* xq = (const float*)d_in[0];
    const float* xk = (const float*)d_in[1];
    const float* xv = (const float*)d_in[2];
    const int* pmask = (const int*)d_in[3];
    const float* Wq = (const float*)d_in[4];
    const float* bq = (const float*)d_in[5];
    const float* Wk = (const float*)d_in[6];
    const float* bk = (const float*)d_in[7];
    const float* Wv = (const float*)d_in[8];
    const float* bv = (const float*)d_in[9];
    const float* Wo = (const float*)d_in[10];
    const float* bo = (const float*)d_in[11];

    char* ws = (char*)d_ws;
    const size_t WT = (size_t)DM * DM * 2;             // 2 MB per transposed weight
    const size_t QKV = (size_t)NB * NH * TT * HD * 2;  // 16 MB each
    unsigned short* WqT = (unsigned short*)(ws + 0 * WT);
    unsigned short* WkT = (unsigned short*)(ws + 1 * WT);
    unsigned short* WvT = (unsigned short*)(ws + 2 * WT);
    unsigned short* WoT = (unsigned short*)(ws + 3 * WT);
    unsigned short* Qb = (unsigned short*)(ws + 4 * WT);
    unsigned short* Kb = (unsigned short*)(ws + 4 * WT + QKV);
    unsigned short* Vb = (unsigned short*)(ws + 4 * WT + 2 * QKV);
    unsigned short* Vt = (unsigned short*)(ws + 4 * WT + 3 * QKV);
    unsigned short* Xb = (unsigned short*)(ws + 4 * WT + 4 * QKV);  // reused x-bf16
    unsigned short* Ob = Vb;  // Vb dead after k_transpose_v; reuse for attn out

    dim3 tb(32, 8);
    k_transpose_w<<<dim3(32, 32), tb, 0, stream>>>(Wq, WqT);
    k_transpose_w<<<dim3(32, 32), tb, 0, stream>>>(Wk, WkT);
    k_transpose_w<<<dim3(32, 32), tb, 0, stream>>>(Wv, WvT);
    k_transpose_w<<<dim3(32, 32), tb, 0, stream>>>(Wo, WoT);

    const float qscale = 0.125f * 1.44269504088896340736f;  // 1/sqrt(64) * log2(e)
    const int n8 = NB * TT * DM / 8;
    dim3 gg(64, 8);  // M/128, N/128

    k_cvt_bf16<<<2048, 256, 0, stream>>>(xq, Xb, n8);
    k_gemm<0><<<gg, 256, 0, stream>>>(Xb, WqT, bq, Qb, qscale);
    k_cvt_bf16<<<2048, 256, 0, stream>>>(xk, Xb, n8);
    k_gemm<0><<<gg, 256, 0, stream>>>(Xb, WkT, bk, Kb, 1.0f);
    k_cvt_bf16<<<2048, 256, 0, stream>>>(xv, Xb, n8);
    k_gemm<0><<<gg, 256, 0, stream>>>(Xb, WvT, bv, Vb, 1.0f);

    k_transpose_v<<<dim3(TT / 32, HD / 32, NB * NH), tb, 0, stream>>>(Vb, Vt);

    k_attn<<<dim3((TT / QBLK) * NB * NH), 512, 0, stream>>>(Qb, Kb, Vt, pmask, Ob);

    k_gemm<1><<<gg, 256, 0, stream>>>(Ob, WoT, bo, d_out, 1.0f);
}

// Round 11
// 216.591 us; speedup vs baseline: 1.4367x; 1.1216x over previous
//
#include <hip/hip_runtime.h>
#include <hip/hip_bf16.h>
#include <cstdint>

#define NB 4
#define TT 2048
#define DM 1024
#define NH 16
#define HD 64
#define QBLK 256
#define KVB 64

typedef __attribute__((ext_vector_type(8))) short bf16x8;
typedef __attribute__((ext_vector_type(4))) float f32x4;
typedef __attribute__((ext_vector_type(16))) float f32x16;
typedef __attribute__((ext_vector_type(4))) float float4v;
typedef __attribute__((ext_vector_type(4))) int i32x4;

static __device__ __forceinline__ unsigned short f2bf(float x) {
    unsigned int u = __float_as_uint(x);
    unsigned int r = (u + 0x7fffu + ((u >> 16) & 1u)) >> 16;
    return (unsigned short)r;
}
static __device__ __forceinline__ uint32_t pk2bf(float lo, float hi) {
    return (uint32_t)f2bf(lo) | ((uint32_t)f2bf(hi) << 16);
}

#define GLOAD16(gp, lp) __builtin_amdgcn_global_load_lds(                 \
    (const __attribute__((address_space(1))) void*)(gp),                  \
    (__attribute__((address_space(3))) void*)(lp), 16, 0, 0)
#define BAR() asm volatile("s_barrier" ::: "memory")
#define WAITV8() asm volatile("s_waitcnt vmcnt(8)" ::: "memory")
#define WAITV2() asm volatile("s_waitcnt vmcnt(2)" ::: "memory")
#define WAITV0() asm volatile("s_waitcnt vmcnt(0)" ::: "memory")

// ---- f32 -> bf16 bulk convert, 3 tensors in one launch (grid.y selects) ----
__global__ __launch_bounds__(256) void k_cvt3(const float* __restrict__ sq,
                                              const float* __restrict__ sk,
                                              const float* __restrict__ sv,
                                              unsigned short* __restrict__ dst,
                                              int n8) {
    const int z = blockIdx.y;
    const float* s = (z == 0) ? sq : (z == 1) ? sk : sv;
    unsigned short* d = dst + (size_t)z * n8 * 8;
    int i = blockIdx.x * 256 + threadIdx.x;
    const int stride = gridDim.x * 256;
    for (; i < n8; i += stride) {
        const float4v* sp = (const float4v*)(s + (size_t)i * 8);
        float4v v0 = sp[0], v1 = sp[1];
        uint4 o;
        o.x = pk2bf(v0[0], v0[1]);
        o.y = pk2bf(v0[2], v0[3]);
        o.z = pk2bf(v1[0], v1[1]);
        o.w = pk2bf(v1[2], v1[3]);
        *(uint4*)(d + (size_t)i * 8) = o;
    }
}

// ---- W[k][n] f32 -> Wt[n][k] bf16 (transpose + convert) ----
__global__ __launch_bounds__(256) void k_transpose_w(const float* __restrict__ W,
                                                     unsigned short* __restrict__ Wt) {
    __shared__ unsigned short tile[32][33];
    int tx = threadIdx.x, ty = threadIdx.y;
    int kb = blockIdx.x * 32, nb = blockIdx.y * 32;
#pragma unroll
    for (int i = 0; i < 4; ++i)
        tile[ty + i * 8][tx] = f2bf(W[(size_t)(kb + ty + i * 8) * DM + nb + tx]);
    __syncthreads();
#pragma unroll
    for (int i = 0; i < 4; ++i)
        Wt[(size_t)(nb + ty + i * 8) * DM + kb + tx] = tile[tx][ty + i * 8];
}

// ---- V[bh][t][d] bf16 -> Vt[bh][d][t] bf16 ----
__global__ __launch_bounds__(256) void k_transpose_v(const unsigned short* __restrict__ V,
                                                     unsigned short* __restrict__ Vt) {
    __shared__ unsigned short tile[32][34];
    int tx = threadIdx.x, ty = threadIdx.y;
    int bh = blockIdx.z;
    int t0 = blockIdx.x * 32, d0 = blockIdx.y * 32;
    const unsigned short* src = V + (size_t)bh * TT * HD;
    unsigned short* dst = Vt + (size_t)bh * HD * TT;
#pragma unroll
    for (int i = 0; i < 4; ++i)
        tile[ty + i * 8][tx] = src[(size_t)(t0 + ty + i * 8) * HD + d0 + tx];
    __syncthreads();
#pragma unroll
    for (int i = 0; i < 4; ++i)
        dst[(size_t)(d0 + ty + i * 8) * TT + t0 + tx] = tile[tx][ty + i * 8];
}

// ---- GEMM: C = A_bf16 @ W (+bias)*scale, BK=64, m97-style staging ----
// BATCHED==1: grid.z in {0,1,2} selects A/W/bias/out (QKV projections, scatter
// to [b,h,t,d] bf16). BATCHED==0: single f32 row-major output (Wo GEMM).
template <int BATCHED>
__global__ __launch_bounds__(256) void k_gemm(const unsigned short* __restrict__ A0,
                                              const unsigned short* __restrict__ Bt0,
                                              const float* __restrict__ bias0,
                                              const float* __restrict__ bias1,
                                              const float* __restrict__ bias2,
                                              void* __restrict__ Cv, float scale0) {
    __shared__ __align__(16) char Asl[2][16384];
    __shared__ __align__(16) char Bsl[2][16384];
    const int tid = threadIdx.x;
    const int lane = tid & 63, wid = tid >> 6;
    const int lg = lane >> 4, lc = lane & 15;
    const int wm = wid >> 1, wn = wid & 1;
    const int m0 = blockIdx.x * 128, n0 = blockIdx.y * 128;
    const int z = BATCHED ? blockIdx.z : 0;

    const char* Ab = (const char*)(A0 + (size_t)z * NB * TT * DM);
    const char* Bb = (const char*)(Bt0 + (size_t)z * DM * DM);
    const float* bias = (z == 0) ? bias0 : (z == 1) ? bias1 : bias2;
    const float scale = (BATCHED && z != 0) ? 1.0f : scale0;

    f32x4 acc[4][4];
#pragma unroll
    for (int mi = 0; mi < 4; ++mi)
#pragma unroll
        for (int ni = 0; ni < 4; ++ni)
            acc[mi][ni] = (f32x4){0.f, 0.f, 0.f, 0.f};

    auto stage = [&](int buf, int k0) {
#pragma unroll
        for (int j = 0; j < 4; ++j) {
            const int row = j * 32 + (tid >> 3);
            const int swz = ((tid & 7) * 16) ^ ((row & 7) << 4);
            GLOAD16(Ab + (size_t)(m0 + row) * (DM * 2) + k0 * 2 + swz,
                    &Asl[buf][0] + j * 4096 + tid * 16);
            GLOAD16(Bb + (size_t)(n0 + row) * (DM * 2) + k0 * 2 + swz,
                    &Bsl[buf][0] + j * 4096 + tid * 16);
        }
    };

    stage(0, 0);
    __syncthreads();  // drains vmcnt(0) for the prologue tile

    int cur = 0;
    for (int t = 0; t < DM / 64; ++t) {
        if (t + 1 < DM / 64) {
            stage(cur ^ 1, (t + 1) * 64);
            WAITV8();  // current tile's 8 loads done; next tile's 8 in flight
        } else {
            WAITV0();
        }
        BAR();

#pragma unroll
        for (int kk = 0; kk < 2; ++kk) {
            bf16x8 af[4], bfr[4];
#pragma unroll
            for (int ni = 0; ni < 4; ++ni) {
                const int n = wn * 64 + ni * 16 + lc;
                bfr[ni] = *(const bf16x8*)(&Bsl[cur][0] + n * 128 +
                                           ((kk * 64 + lg * 16) ^ ((n & 7) << 4)));
            }
#pragma unroll
            for (int mi = 0; mi < 4; ++mi) {
                const int m = wm * 64 + mi * 16 + lc;
                af[mi] = *(const bf16x8*)(&Asl[cur][0] + m * 128 +
                                          ((kk * 64 + lg * 16) ^ ((m & 7) << 4)));
            }
            __builtin_amdgcn_s_setprio(1);
#pragma unroll
            for (int mi = 0; mi < 4; ++mi)
#pragma unroll
                for (int ni = 0; ni < 4; ++ni)
                    acc[mi][ni] = __builtin_amdgcn_mfma_f32_16x16x32_bf16(af[mi], bfr[ni],
                                                                          acc[mi][ni], 0, 0, 0);
            __builtin_amdgcn_s_setprio(0);
        }
        BAR();
        cur ^= 1;
    }

#pragma unroll
    for (int mi = 0; mi < 4; ++mi)
#pragma unroll
        for (int ni = 0; ni < 4; ++ni)
#pragma unroll
            for (int r = 0; r < 4; ++r) {
                int m = m0 + wm * 64 + mi * 16 + lg * 4 + r;
                int n = n0 + wn * 64 + ni * 16 + lc;
                float val = (acc[mi][ni][r] + bias[n]) * scale;
                if (BATCHED) {
                    int b = m >> 11, t = m & (TT - 1), h = n >> 6, d = n & 63;
                    ((unsigned short*)Cv)[(size_t)z * NB * NH * TT * HD +
                                          (((size_t)b * NH + h) * TT + t) * HD + d] = f2bf(val);
                } else {
                    ((float*)Cv)[(size_t)m * DM + n] = val;
                }
            }
}

// ---- flash attention, swapped-QK^T 32x32 MFMA, in-register softmax ----
// 8 waves x 32 q-rows (QBLK=256). KV tiles of 64, double-buffered LDS in
// fragment order (16B chunk c of row r at (c*64+r)*16 — conflict-free reads).
// Grid 512, 1-D. HW places blocks i and i+256 on the same CU (8 XCD x 32 CU
// round-robin), so the two halves get complementary causal loads:
// half=idx>>8, r=idx&255: bh=r>>2 (same head in both halves -> L2 reuse),
// qb = half ? 7-(r&3) : (r&3) -> per-CU tile count constant (36).
// S^T = mfma(K, Q): col=lane&31=q, reg r holds key (r&3)+8*(r>>2)+4*(lane>>5).
__global__ __launch_bounds__(512) void k_attn(const unsigned short* __restrict__ Qg,
                                              const unsigned short* __restrict__ Kg,
                                              const unsigned short* __restrict__ Vtg,
                                              const int* __restrict__ pm,
                                              unsigned short* __restrict__ Og) {
    __shared__ __align__(16) unsigned short Kl[2][KVB * HD];  // 8 KB per buf
    __shared__ __align__(16) unsigned short Vl[2][KVB * HD];  // V^T tile, frag order
    __shared__ uint64_t pmbits[TT / 64];

    const int idx = blockIdx.x;
    const int half = idx >> 8, r5 = idx & 255;
    const int a = r5 & 3;
    const int qb = half ? (7 - a) : a;
    const int bh = r5 >> 2;
    const int b = bh >> 4, h = bh & 15;
    const int qbase = qb * QBLK;
    const int tid = threadIdx.x;
    const int wid = tid >> 6, lane = tid & 63;
    const int hi = lane >> 5, l31 = lane & 31;
    const int q0 = qbase + wid * 32;
    const int q = q0 + l31;

    const unsigned short* Qh = Qg + (size_t)bh * TT * HD;
    const char* Khb = (const char*)(Kg + (size_t)bh * TT * HD);
    const char* Vthb = (const char*)(Vtg + (size_t)bh * HD * TT);
    const int* pmb = pm + b * TT;

    char* const kdst = (char*)&Kl[0][0];
    char* const vdst = (char*)&Vl[0][0];

    // prologue: stage tile 0 (drained by the __syncthreads below).
    // Wave wid stages chunk c=wid for all 64 rows: lane = key (K) / d (V).
    GLOAD16(Khb + (size_t)lane * 128 + wid * 16, kdst + tid * 16);
    GLOAD16(Vthb + (size_t)lane * 4096 + wid * 16, vdst + tid * 16);

    // padding-mask bitmasks (one u64 per 64-key tile); bit=1 -> key valid
#pragma unroll
    for (int it = 0; it < 4; ++it) {
        const int g = wid + it * 8;
        unsigned long long msk = __ballot(pmb[g * 64 + lane] != 0);
        if (lane == 0) pmbits[g] = msk;
    }

    // hoist Q fragments (B-operand: col q = lane&31, d-chunk dd*16 + hi*8)
    bf16x8 qf[4];
#pragma unroll
    for (int dd = 0; dd < 4; ++dd)
        qf[dd] = *(const bf16x8*)((const char*)Qh + (size_t)q * 128 + dd * 32 + hi * 16);

    f32x16 o0, o1;
#pragma unroll
    for (int r = 0; r < 16; ++r) { o0[r] = 0.f; o1[r] = 0.f; }
    float mrow = -INFINITY, msafe = -1.0e30f, lrow = 0.f;

    __syncthreads();  // pmbits visible; tile-0 loads drained (vmcnt 0)

    const int nt = (qbase + QBLK) >> 6;
    int cur = 0;
    for (int t = 0; t < nt; ++t) {
        const int kv0 = t << 6;
        if (t + 1 < nt) {
            const int kn = kv0 + KVB;
            const int nb = (cur ^ 1) * 8192 + tid * 16;
            GLOAD16(Khb + (size_t)(kn + lane) * 128 + wid * 16, kdst + nb);
            GLOAD16(Vthb + (size_t)lane * 4096 + (size_t)kn * 2 + wid * 16, vdst + nb);
            WAITV2();  // current tile's 2 loads done; next tile's 2 in flight
        } else {
            WAITV0();
        }
        BAR();

        if (kv0 <= q0 + 31) {  // wave-uniform causal skip
            const uint64_t vb = pmbits[kv0 >> 6];
            const uint32_t pm0 = ((uint32_t)vb) >> (4 * hi);
            const uint32_t pm1 = ((uint32_t)(vb >> 32)) >> (4 * hi);
            const bool allvalid = (vb == ~0ull);
            const bool do2 = (kv0 + 32 <= q0 + 31);
            const bool needmask = (kv0 + 63 > q0) || !allvalid;
            const char* kb = (const char*)&Kl[0][0] + cur * 8192;
            const char* vbp = (const char*)&Vl[0][0] + cur * 8192;

            // ---- QK^T: S^T[key][q] ----
            f32x16 st0, st1;
#pragma unroll
            for (int r = 0; r < 16; ++r) { st0[r] = 0.f; st1[r] = 0.f; }
            __builtin_amdgcn_s_setprio(1);
#pragma unroll
            for (int dd = 0; dd < 4; ++dd) {
                const char* kchunk = kb + (dd * 2 + hi) * 1024;
                bf16x8 kf = *(const bf16x8*)(kchunk + l31 * 16);
                st0 = __builtin_amdgcn_mfma_f32_32x32x16_bf16(kf, qf[dd], st0, 0, 0, 0);
            }
            if (do2) {
#pragma unroll
                for (int dd = 0; dd < 4; ++dd) {
                    const char* kchunk = kb + (dd * 2 + hi) * 1024;
                    bf16x8 kf = *(const bf16x8*)(kchunk + 512 + l31 * 16);
                    st1 = __builtin_amdgcn_mfma_f32_32x32x16_bf16(kf, qf[dd], st1, 0, 0, 0);
                }
            }
            __builtin_amdgcn_s_setprio(0);

            // ---- masking (causal + padding), lane-local ----
            const int qr = q - kv0 - 4 * hi;
            if (needmask) {
#pragma unroll
                for (int r = 0; r < 16; ++r) {
                    const int c = (r & 3) + 8 * (r >> 2);
                    st0[r] = (((pm0 >> c) & 1) && (c <= qr)) ? st0[r] : -INFINITY;
                }
                if (do2) {
#pragma unroll
                    for (int r = 0; r < 16; ++r) {
                        const int c = (r & 3) + 8 * (r >> 2);
                        st1[r] = (((pm1 >> c) & 1) && (c + 32 <= qr)) ? st1[r] : -INFINITY;
                    }
                }
            }

            // ---- online softmax, in-register, defer-max (T13) ----
            float mloc = -INFINITY;
#pragma unroll
            for (int r = 0; r < 16; ++r) mloc = fmaxf(mloc, st0[r]);
            if (do2) {
#pragma unroll
                for (int r = 0; r < 16; ++r) mloc = fmaxf(mloc, st1[r]);
            }
            const float cmax = fmaxf(mloc, __shfl_xor(mloc, 32, 64));
            // rescale only when max moved >8 (exp2 domain); invariant
            // msafe == max(mrow, -1e30) holds (deferral updates neither).
            if (!__all(cmax - mrow <= 8.0f)) {
                const float mnew = fmaxf(mrow, cmax);
                const float ms = fmaxf(mnew, -1.0e30f);
                const float esc = __builtin_amdgcn_exp2f(mrow - ms);  // -inf -> 0
#pragma unroll
                for (int r = 0; r < 16; ++r) { o0[r] *= esc; o1[r] *= esc; }
                lrow *= esc;
                mrow = mnew;
                msafe = ms;
            }

            // exponentials vs finite msafe (masked -inf -> 0; bounded by 2^8)
            float tot = 0.f;
#pragma unroll
            for (int r = 0; r < 16; ++r) {
                st0[r] = __builtin_amdgcn_exp2f(st0[r] - msafe);
                tot += st0[r];
            }
            if (do2) {
#pragma unroll
                for (int r = 0; r < 16; ++r) {
                    st1[r] = __builtin_amdgcn_exp2f(st1[r] - msafe);
                    tot += st1[r];
                }
            }
            lrow += tot + __shfl_xor(tot, 32, 64);

            // ---- P -> bf16 B-fragments (pair redistribution via shfl) + PV ----
            __builtin_amdgcn_s_setprio(1);
#pragma unroll
            for (int kc = 0; kc < 2; ++kc) {
                uint32_t A0 = pk2bf(st0[kc * 8 + 0], st0[kc * 8 + 1]);
                uint32_t A1 = pk2bf(st0[kc * 8 + 2], st0[kc * 8 + 3]);
                uint32_t C0 = pk2bf(st0[kc * 8 + 4], st0[kc * 8 + 5]);
                uint32_t C1 = pk2bf(st0[kc * 8 + 6], st0[kc * 8 + 7]);
                uint32_t oA0 = __shfl_xor(A0, 32, 64), oA1 = __shfl_xor(A1, 32, 64);
                uint32_t oC0 = __shfl_xor(C0, 32, 64), oC1 = __shfl_xor(C1, 32, 64);
                i32x4 pf = {(int)(hi ? oC0 : A0), (int)(hi ? oC1 : A1),
                            (int)(hi ? C0 : oA0), (int)(hi ? C1 : oA1)};
                bf16x8 pb = *(bf16x8*)&pf;
                const char* vchunk = vbp + (kc * 2 + hi) * 1024;
                {
                    bf16x8 vf = *(const bf16x8*)(vchunk + l31 * 16);
                    o0 = __builtin_amdgcn_mfma_f32_32x32x16_bf16(vf, pb, o0, 0, 0, 0);
                }
                {
                    bf16x8 vf = *(const bf16x8*)(vchunk + 512 + l31 * 16);
                    o1 = __builtin_amdgcn_mfma_f32_32x32x16_bf16(vf, pb, o1, 0, 0, 0);
                }
            }
            if (do2) {
#pragma unroll
                for (int kc = 0; kc < 2; ++kc) {
                    uint32_t A0 = pk2bf(st1[kc * 8 + 0], st1[kc * 8 + 1]);
                    uint32_t A1 = pk2bf(st1[kc * 8 + 2], st1[kc * 8 + 3]);
                    uint32_t C0 = pk2bf(st1[kc * 8 + 4], st1[kc * 8 + 5]);
                    uint32_t C1 = pk2bf(st1[kc * 8 + 6], st1[kc * 8 + 7]);
                    uint32_t oA0 = __shfl_xor(A0, 32, 64), oA1 = __shfl_xor(A1, 32, 64);
                    uint32_t oC0 = __shfl_xor(C0, 32, 64), oC1 = __shfl_xor(C1, 32, 64);
                    i32x4 pf = {(int)(hi ? oC0 : A0), (int)(hi ? oC1 : A1),
                                (int)(hi ? C0 : oA0), (int)(hi ? C1 : oA1)};
                    bf16x8 pb = *(bf16x8*)&pf;
                    const char* vchunk = vbp + (4 + kc * 2 + hi) * 1024;
                    {
                        bf16x8 vf = *(const bf16x8*)(vchunk + l31 * 16);
                        o0 = __builtin_amdgcn_mfma_f32_32x32x16_bf16(vf, pb, o0, 0, 0, 0);
                    }
                    {
                        bf16x8 vf = *(const bf16x8*)(vchunk + 512 + l31 * 16);
                        o1 = __builtin_amdgcn_mfma_f32_32x32x16_bf16(vf, pb, o1, 0, 0, 0);
                    }
                }
            }
            __builtin_amdgcn_s_setprio(0);
        }
        BAR();
        cur ^= 1;
    }

    // ---- epilogue: normalize, write bf16 [b*T+q][h*64+d], 8B packed stores ----
    const float inv = (lrow > 0.f) ? (1.0f / lrow) : 0.f;
    unsigned short* orow = Og + ((size_t)(b * TT + q)) * DM + h * HD;
#pragma unroll
    for (int g4 = 0; g4 < 4; ++g4) {
        uint32_t w0 = pk2bf(o0[g4 * 4 + 0] * inv, o0[g4 * 4 + 1] * inv);
        uint32_t w1 = pk2bf(o0[g4 * 4 + 2] * inv, o0[g4 * 4 + 3] * inv);
        *(uint2*)(orow + g4 * 8 + 4 * hi) = make_uint2(w0, w1);
    }
#pragma unroll
    for (int g4 = 0; g4 < 4; ++g4) {
        uint32_t w0 = pk2bf(o1[g4 * 4 + 0] * inv, o1[g4 * 4 + 1] * inv);
        uint32_t w1 = pk2bf(o1[g4 * 4 + 2] * inv, o1[g4 * 4 + 3] * inv);
        *(uint2*)(orow + 32 + g4 * 8 + 4 * hi) = make_uint2(w0, w1);
    }
}

extern "C" void kernel_launch(void* const* d_in, const int* in_sizes, int n_in,
                              void* d_out, int out_size, void* d_ws, size_t ws_size,
                              hipStream_t stream) {
    const float* xq = (const float*)d_in[0];
    const float* xk = (const float*)d_in[1];
    const float* xv = (const float*)d_in[2];
    const int* pmask = (const int*)d_in[3];
    const float* Wq = (const float*)d_in[4];
    const float* bq = (const float*)d_in[5];
    const float* Wk = (const float*)d_in[6];
    const float* bk = (const float*)d_in[7];
    const float* Wv = (const float*)d_in[8];
    const float* bv = (const float*)d_in[9];
    const float* Wo = (const float*)d_in[10];
    const float* bo = (const float*)d_in[11];

    char* ws = (char*)d_ws;
    const size_t WT = (size_t)DM * DM * 2;             // 2 MB per transposed weight
    const size_t QKV = (size_t)NB * NH * TT * HD * 2;  // 16 MB each
    unsigned short* WqT = (unsigned short*)(ws + 0 * WT);   // WqT/WkT/WvT contiguous
    unsigned short* WoT = (unsigned short*)(ws + 3 * WT);
    unsigned short* Qb = (unsigned short*)(ws + 4 * WT);    // Qb/Kb/Vb contiguous
    unsigned short* Kb = (unsigned short*)(ws + 4 * WT + QKV);
    unsigned short* Vb = (unsigned short*)(ws + 4 * WT + 2 * QKV);
    unsigned short* Vt = (unsigned short*)(ws + 4 * WT + 3 * QKV);
    unsigned short* Xb = (unsigned short*)(ws + 4 * WT + 4 * QKV);  // Xq/Xk/Xv (48 MB)
    unsigned short* Ob = Vb;  // Vb dead after k_transpose_v; reuse for attn out

    dim3 tb(32, 8);
    k_transpose_w<<<dim3(32, 32), tb, 0, stream>>>(Wq, WqT);
    k_transpose_w<<<dim3(32, 32), tb, 0, stream>>>(Wk, WqT + DM * DM);
    k_transpose_w<<<dim3(32, 32), tb, 0, stream>>>(Wv, WqT + 2 * DM * DM);
    k_transpose_w<<<dim3(32, 32), tb, 0, stream>>>(Wo, WoT);

    const float qscale = 0.125f * 1.44269504088896340736f;  // 1/sqrt(64) * log2(e)
    const int n8 = NB * TT * DM / 8;

    k_cvt3<<<dim3(1024, 3), 256, 0, stream>>>(xq, xk, xv, Xb, n8);
    k_gemm<1><<<dim3(64, 8, 3), 256, 0, stream>>>(Xb, WqT, bq, bk, bv, Qb, qscale);

    k_transpose_v<<<dim3(TT / 32, HD / 32, NB * NH), tb, 0, stream>>>(Vb, Vt);

    k_attn<<<dim3((TT / QBLK) * NB * NH), 512, 0, stream>>>(Qb, Kb, Vt, pmask, Ob);

    k_gemm<0><<<dim3(64, 8, 1), 256, 0, stream>>>(Ob, WoT, bo, bo, bo, d_out, 1.0f);
}